// Round 1
// 3554.739 us; speedup vs baseline: 1.6224x; 1.6224x over previous
//
#include <hip/hip_runtime.h>
#include <math.h>

#define CDIV(a,b) (((a)+(b)-1)/(b))

static constexpr int NE  = 512;   // n_embed
static constexpr int EH  = 8;     // encoder heads
static constexpr int EHD = 64;    // encoder head dim
static constexpr int DHN = 16;    // decoder heads
static constexpr int HDD = 32;    // decoder head dim
static constexpr int NM  = 80;    // mels
static constexpr int TMl = 1500;  // mel time
static constexpr int TP  = 1502;  // padded time
static constexpr int TA  = 750;   // audio ctx
static constexpr int LQ  = 448;   // text ctx
static constexpr int NB  = 4;     // batch
static constexpr int OV  = 51904; // padded vocab

typedef __attribute__((ext_vector_type(8))) short bf16x8;
typedef __attribute__((ext_vector_type(8))) unsigned short us8;
typedef __attribute__((ext_vector_type(4))) float f32x4;

// ---------------- elementwise / layout kernels ----------------

__global__ void k_transpose_mels(const float* __restrict__ mels, float* __restrict__ melsT) {
    long idx = (long)blockIdx.x * blockDim.x + threadIdx.x;
    long total = (long)NB * TP * NM;
    if (idx >= total) return;
    int ci = (int)(idx % NM);
    int t  = (int)((idx / NM) % TP);
    int b  = (int)(idx / ((long)NM * TP));
    float v = 0.f;
    if (t >= 1 && t <= TMl) v = mels[((long)b * NM + ci) * TMl + (t - 1)];
    melsT[idx] = v;
}

__global__ void k_zero_x1t_pads(float* __restrict__ x1t) {
    int idx = blockIdx.x * blockDim.x + threadIdx.x;
    if (idx >= NB * 2 * NE) return;
    int c = idx % NE;
    int r = (idx / NE) % 2;
    int b = idx / (NE * 2);
    int t = r ? (TP - 1) : 0;
    x1t[((long)b * TP + t) * NE + c] = 0.f;
}

__global__ void k_repack_w(const float* __restrict__ w, float* __restrict__ wr, int O, int I) {
    // w[o][i][k] -> wr[k][o][i]
    long idx = (long)blockIdx.x * blockDim.x + threadIdx.x;
    long total = (long)O * I * 3;
    if (idx >= total) return;
    int k = (int)(idx % 3);
    int i = (int)((idx / 3) % I);
    int o = (int)(idx / ((long)3 * I));
    wr[((long)k * O + o) * I + i] = w[idx];
}

__global__ void k_add_encpos(float* __restrict__ x) {
    long idx = (long)blockIdx.x * blockDim.x + threadIdx.x;
    long total = (long)NB * TA * NE;
    if (idx >= total) return;
    int c = (int)(idx % NE);
    int t = (int)((idx / NE) % TA);
    double inc = log(10000.0) / 255.0;
    int j = c & 255;
    double st = (double)t * exp(-inc * (double)j);
    float p = (c < 256) ? (float)sin(st) : (float)cos(st);
    x[idx] += p;
}

__global__ void k_embed(const int* __restrict__ ids, const float* __restrict__ ew,
                        const float* __restrict__ pos, float* __restrict__ ctx) {
    long idx = (long)blockIdx.x * blockDim.x + threadIdx.x;
    long total = (long)NB * LQ * NE;
    if (idx >= total) return;
    int c = (int)(idx % NE);
    int t = (int)((idx / NE) % LQ);
    int b = (int)(idx / ((long)NE * LQ));
    int id = ids[b * LQ + t];
    float v = ew[(long)id * NE + c] * 22.62741699796952f;
    if (t >= 1) v += pos[(long)(t - 1) * NE + c];
    ctx[idx] = v;
}

__global__ void k_bcast_pos(const float* __restrict__ pos, float* __restrict__ dst, int Bn) {
    long idx = (long)blockIdx.x * blockDim.x + threadIdx.x;
    long total = (long)Bn * LQ * NE;
    if (idx >= total) return;
    int c = (int)(idx % NE);
    int t = (int)((idx / NE) % LQ);
    dst[idx] = pos[(long)t * NE + c];
}

__global__ void k_ropetab(float* __restrict__ ctab, float* __restrict__ stab) {
    int idx = blockIdx.x * blockDim.x + threadIdx.x;
    if (idx >= LQ * 16) return;
    int m = idx % 16;
    int t = idx / 16;
    double inv = pow(10000.0, -(double)(2 * m) / 32.0);
    double f = (double)t * inv;
    ctab[idx] = (float)cos(f);
    stab[idx] = (float)sin(f);
}

__global__ void k_rope(float* __restrict__ x, int Bn, int shiftK,
                       const float* __restrict__ ctab, const float* __restrict__ stab) {
    long idx = (long)blockIdx.x * blockDim.x + threadIdx.x;
    long total = (long)Bn * LQ * DHN * 16;
    if (idx >= total) return;
    int m = (int)(idx % 16);
    int h = (int)((idx / 16) % DHN);
    int t = (int)((idx / (16 * DHN)) % LQ);
    int b = (int)(idx / ((long)16 * DHN * LQ));
    int tt = shiftK ? (t > 0 ? t - 1 : 0) : t;
    float c = ctab[tt * 16 + m];
    float s = stab[tt * 16 + m];
    long base = (((long)b * LQ + t) * DHN + h) * HDD;
    float x1 = x[base + m];
    float x2 = x[base + 16 + m];
    x[base + m]      = x1 * c + x2 * s;
    x[base + 16 + m] = -x1 * s + x2 * c;
}

// ---------------- rms / decorrelate / softmax ----------------

__global__ void k_rms512(const float* __restrict__ src, float* __restrict__ dst, int rows) {
    int wave = blockIdx.x * (blockDim.x >> 6) + (threadIdx.x >> 6);
    int lane = threadIdx.x & 63;
    if (wave >= rows) return;
    const float* s = src + (long)wave * NE;
    float4 a = *(const float4*)(s + lane * 4);
    float4 b = *(const float4*)(s + 256 + lane * 4);
    float ss = a.x*a.x + a.y*a.y + a.z*a.z + a.w*a.w
             + b.x*b.x + b.y*b.y + b.z*b.z + b.w*b.w;
    for (int m = 32; m >= 1; m >>= 1) ss += __shfl_xor(ss, m, 64);
    float sc = rsqrtf(ss / 512.f + 1e-6f);
    float* d = dst + (long)wave * NE;
    a.x *= sc; a.y *= sc; a.z *= sc; a.w *= sc;
    b.x *= sc; b.y *= sc; b.z *= sc; b.w *= sc;
    *(float4*)(d + lane * 4) = a;
    *(float4*)(d + 256 + lane * 4) = b;
}

template<int D>
__global__ void k_rms_heads(float* __restrict__ x, long rows) {
    const int RPW = 64 / D;
    long wave = (long)blockIdx.x * (blockDim.x >> 6) + (threadIdx.x >> 6);
    int lane = threadIdx.x & 63;
    long row = wave * RPW + lane / D;
    if (row >= rows) return;
    int col = lane % D;
    long idx = row * D + col;
    float v = x[idx];
    float ss = v * v;
    for (int m = D / 2; m >= 1; m >>= 1) ss += __shfl_xor(ss, m, 64);
    x[idx] = v * rsqrtf(ss / (float)D + 1e-6f);
}

template<int D>
__global__ void k_decorrelate(float* __restrict__ o, const float* __restrict__ v, long rows) {
    const int RPW = 64 / D;
    long wave = (long)blockIdx.x * (blockDim.x >> 6) + (threadIdx.x >> 6);
    int lane = threadIdx.x & 63;
    long row = wave * RPW + lane / D;
    if (row >= rows) return;
    int col = lane % D;
    long idx = row * D + col;
    float ov = o[idx];
    float vv = v[idx];
    float dov = ov * vv;
    float dvv = vv * vv;
    for (int m = D / 2; m >= 1; m >>= 1) {
        dov += __shfl_xor(dov, m, 64);
        dvv += __shfl_xor(dvv, m, 64);
    }
    float nv = sqrtf(dvv);
    float c = fmaxf(nv, 1e-9f);
    o[idx] = ov - (dov / (c * c)) * vv;
}

__global__ void k_softmax(float* __restrict__ s, int H, int Lq, int Lk,
                          int causal, const int* __restrict__ ids, long nrows) {
    long row = (long)blockIdx.x * (blockDim.x >> 6) + (threadIdx.x >> 6);
    if (row >= nrows) return;
    int lane = threadIdx.x & 63;
    int qt = (int)(row % Lq);
    long z = row / Lq;
    int b = (int)(z / H);
    float* p = s + row * (long)Lk;
    int cnt = (Lk + 63) >> 6;
    float vals[12];
    float mx = -INFINITY;
    for (int i = 0; i < cnt; i++) {
        int k = lane + (i << 6);
        float v = -INFINITY;
        if (k < Lk) {
            v = p[k];
            if (causal && k > qt) v = -INFINITY;
            if (ids && ids[(long)b * Lk + k] == 0) v = -INFINITY;
        }
        vals[i] = v;
        mx = fmaxf(mx, v);
    }
    for (int m = 32; m >= 1; m >>= 1) mx = fmaxf(mx, __shfl_xor(mx, m, 64));
    float sum = 0.f;
    for (int i = 0; i < cnt; i++) {
        float e = expf(vals[i] - mx);
        vals[i] = e;
        sum += e;
    }
    for (int m = 32; m >= 1; m >>= 1) sum += __shfl_xor(sum, m, 64);
    float inv = 1.f / sum;
    for (int i = 0; i < cnt; i++) {
        int k = lane + (i << 6);
        if (k < Lk) p[k] = vals[i] * inv;
    }
}

// ---------------- fp32 batched GEMM (conv + attention only) ----------------

template<bool TRANSB>
__global__ __launch_bounds__(256) void k_gemm(
    const float* __restrict__ A, const float* __restrict__ Bm,
    const float* __restrict__ bias, float* __restrict__ C,
    int M, int N, int K, int lda, int ldb, int ldc,
    long sAb, long sAh, long sBb, long sBh, long sCb, long sCh, int H,
    float alpha, float beta, int act)
{
    __shared__ __align__(16) float As[16][68];
    __shared__ __align__(16) float Bs[16][68];
    int z = blockIdx.z;
    int bb = z / H, hh = z % H;
    A  += (long)bb * sAb + (long)hh * sAh;
    Bm += (long)bb * sBb + (long)hh * sBh;
    C  += (long)bb * sCb + (long)hh * sCh;
    int m0 = blockIdx.y * 64, n0 = blockIdx.x * 64;
    int tid = threadIdx.x;
    int tm0 = (tid / 16) * 4, tn0 = (tid % 16) * 4;
    float acc[4][4] = {};
    for (int k0 = 0; k0 < K; k0 += 16) {
        {
            int k = tid & 15, mr = tid >> 4;
            #pragma unroll
            for (int i = 0; i < 4; i++) {
                int m = mr + i * 16;
                float v = 0.f;
                if (m0 + m < M && k0 + k < K) v = A[(long)(m0 + m) * lda + k0 + k];
                As[k][m] = v;
            }
            if (TRANSB) {
                #pragma unroll
                for (int i = 0; i < 4; i++) {
                    int n = mr + i * 16;
                    float v = 0.f;
                    if (n0 + n < N && k0 + k < K) v = Bm[(long)(n0 + n) * ldb + k0 + k];
                    Bs[k][n] = v;
                }
            } else {
                int n = tid & 63, kr = tid >> 6;
                #pragma unroll
                for (int i = 0; i < 4; i++) {
                    int k2 = kr + i * 4;
                    float v = 0.f;
                    if (k0 + k2 < K && n0 + n < N) v = Bm[(long)(k0 + k2) * ldb + n0 + n];
                    Bs[k2][n] = v;
                }
            }
        }
        __syncthreads();
        #pragma unroll
        for (int kk = 0; kk < 16; kk++) {
            float4 av = *(const float4*)&As[kk][tm0];
            float4 bv = *(const float4*)&Bs[kk][tn0];
            float aa[4] = {av.x, av.y, av.z, av.w};
            float bbv[4] = {bv.x, bv.y, bv.z, bv.w};
            #pragma unroll
            for (int i = 0; i < 4; i++)
                #pragma unroll
                for (int j = 0; j < 4; j++)
                    acc[i][j] += aa[i] * bbv[j];
        }
        __syncthreads();
    }
    #pragma unroll
    for (int i = 0; i < 4; i++) {
        int m = m0 + tm0 + i;
        if (m >= M) continue;
        #pragma unroll
        for (int j = 0; j < 4; j++) {
            int n = n0 + tn0 + j;
            if (n >= N) continue;
            float v = alpha * acc[i][j];
            if (bias) v += bias[n];
            long off = (long)m * ldc + n;
            if (beta != 0.f) v += beta * C[off];
            if (act) v = 0.5f * v * (1.f + erff(v * 0.70710678118654752f));
            C[off] = v;
        }
    }
}

static inline void gemm(hipStream_t st, bool tb, const float* A, const float* Bm,
                        const float* bias, float* C, int M, int N, int K,
                        int lda, int ldb, int ldc,
                        long sAb, long sAh, long sBb, long sBh, long sCb, long sCh,
                        int Z, int H, float alpha, float beta, int act)
{
    dim3 g(CDIV(N, 64), CDIV(M, 64), Z), blk(256);
    if (tb) k_gemm<true ><<<g, blk, 0, st>>>(A, Bm, bias, C, M, N, K, lda, ldb, ldc,
                                             sAb, sAh, sBb, sBh, sCb, sCh, H, alpha, beta, act);
    else    k_gemm<false><<<g, blk, 0, st>>>(A, Bm, bias, C, M, N, K, lda, ldb, ldc,
                                             sAb, sAh, sBb, sBh, sCb, sCh, H, alpha, beta, act);
}

// ---------------- bf16 hi/lo split (Ootomo bf16x3; fp32-level accuracy) ----------------
// hi = trunc-to-bf16(x); lo = bf16(x - hi)  (x - hi is exact in fp32).
// a*b ~= ah*bh + ah*bl + al*bh ; dropped al*bl <= 2^-16 relative.

__global__ void k_split(const float* __restrict__ x, unsigned short* __restrict__ hi,
                        unsigned short* __restrict__ lo, long n4)
{
    long i = (long)blockIdx.x * blockDim.x + threadIdx.x;
    if (i >= n4) return;
    float4 v = ((const float4*)x)[i];
    float f[4] = {v.x, v.y, v.z, v.w};
    unsigned short hh[4], ll[4];
    #pragma unroll
    for (int j = 0; j < 4; ++j) {
        unsigned b = __float_as_uint(f[j]);
        unsigned hb = b & 0xffff0000u;
        float lof = f[j] - __uint_as_float(hb);
        hh[j] = (unsigned short)(hb >> 16);
        ll[j] = (unsigned short)(__float_as_uint(lof) >> 16);
    }
    ushort4 h, l;
    h.x = hh[0]; h.y = hh[1]; h.z = hh[2]; h.w = hh[3];
    l.x = ll[0]; l.y = ll[1]; l.z = ll[2]; l.w = ll[3];
    ((ushort4*)hi)[i] = h;
    ((ushort4*)lo)[i] = l;
}

// ---------------- MFMA GEMM: C[M,N] = A(M,K) . B(N,K)^T  (pre-split bf16 hi/lo) ----------
// 128x128 tile, BK=64, 4 waves (2x2 of 64x64), 16x16x32 bf16 MFMA, 3 passes (hh,hl,lh).
// LDS: 4 planes (Ah,Al,Bh,Bl) of [128 rows][8 granules of 16B], XOR-swizzled g^=(r&7)
// -> conflict-free ds_read_b128 (2 lanes/bank). K must be a multiple of 64 (512/2048 here).

__global__ __launch_bounds__(256, 2) void k_gemm_mf(
    const unsigned short* __restrict__ Ah, const unsigned short* __restrict__ Al,
    const unsigned short* __restrict__ Bh, const unsigned short* __restrict__ Bl,
    const float* __restrict__ bias, float* __restrict__ C,
    int M, int N, int K, int ldc, float beta, int act)
{
    __shared__ unsigned short lds[4 * 8192]; // 64 KB
    const int tid = threadIdx.x;
    const int m0 = blockIdx.y * 128, n0 = blockIdx.x * 128;
    const int wid = tid >> 6, lane = tid & 63;
    const int wm = wid >> 1, wn = wid & 1;
    const int lr = lane & 15, lk = lane >> 4;

    f32x4 acc[4][4] = {};

    for (int k0 = 0; k0 < K; k0 += 64) {
        __syncthreads();
        #pragma unroll
        for (int it = 0; it < 4; ++it) {
            int id = it * 256 + tid;          // 0..1023
            int r = id >> 3, g = id & 7;
            int gs = g ^ (r & 7);
            {
                long aoff = (long)(m0 + r) * K + k0 + g * 8;
                us8 vh = {0,0,0,0,0,0,0,0}, vl = {0,0,0,0,0,0,0,0};
                if (m0 + r < M) {
                    vh = *(const us8*)(Ah + aoff);
                    vl = *(const us8*)(Al + aoff);
                }
                *(us8*)(lds +         (r * 8 + gs) * 8) = vh;
                *(us8*)(lds +  8192 + (r * 8 + gs) * 8) = vl;
            }
            {
                long boff = (long)(n0 + r) * K + k0 + g * 8;
                us8 vh = {0,0,0,0,0,0,0,0}, vl = {0,0,0,0,0,0,0,0};
                if (n0 + r < N) {
                    vh = *(const us8*)(Bh + boff);
                    vl = *(const us8*)(Bl + boff);
                }
                *(us8*)(lds + 16384 + (r * 8 + gs) * 8) = vh;
                *(us8*)(lds + 24576 + (r * 8 + gs) * 8) = vl;
            }
        }
        __syncthreads();
        #pragma unroll
        for (int kc = 0; kc < 2; ++kc) {
            bf16x8 ah[4], al[4], bh[4], bl[4];
            #pragma unroll
            for (int i = 0; i < 4; ++i) {
                int ra = wm * 64 + i * 16 + lr;
                int ga = (kc * 4 + lk) ^ (ra & 7);
                ah[i] = *(const bf16x8*)(lds +         (ra * 8 + ga) * 8);
                al[i] = *(const bf16x8*)(lds +  8192 + (ra * 8 + ga) * 8);
                int rb = wn * 64 + i * 16 + lr;
                int gb = (kc * 4 + lk) ^ (rb & 7);
                bh[i] = *(const bf16x8*)(lds + 16384 + (rb * 8 + gb) * 8);
                bl[i] = *(const bf16x8*)(lds + 24576 + (rb * 8 + gb) * 8);
            }
            #pragma unroll
            for (int i = 0; i < 4; ++i)
                #pragma unroll
                for (int j = 0; j < 4; ++j) {
                    acc[i][j] = __builtin_amdgcn_mfma_f32_16x16x32_bf16(ah[i], bh[j], acc[i][j], 0, 0, 0);
                    acc[i][j] = __builtin_amdgcn_mfma_f32_16x16x32_bf16(ah[i], bl[j], acc[i][j], 0, 0, 0);
                    acc[i][j] = __builtin_amdgcn_mfma_f32_16x16x32_bf16(al[i], bh[j], acc[i][j], 0, 0, 0);
                }
        }
    }
    // epilogue: C/D layout col = lane&15, row = (lane>>4)*4 + reg  [m89-verified]
    #pragma unroll
    for (int i = 0; i < 4; ++i) {
        int rowb = m0 + wm * 64 + i * 16 + lk * 4;
        #pragma unroll
        for (int j = 0; j < 4; ++j) {
            int col = n0 + wn * 64 + j * 16 + lr;
            if (col >= N) continue;
            float bi = bias ? bias[col] : 0.f;
            #pragma unroll
            for (int q = 0; q < 4; ++q) {
                int row = rowb + q;
                if (row >= M) continue;
                float v = acc[i][j][q] + bi;
                long off = (long)row * ldc + col;
                if (beta != 0.f) v += beta * C[off];
                if (act) v = 0.5f * v * (1.f + erff(v * 0.70710678118654752f));
                C[off] = v;
            }
        }
    }
}

// ---------------- launcher ----------------

extern "C" void kernel_launch(void* const* d_in, const int* in_sizes, int n_in,
                              void* d_out, int out_size, void* d_ws, size_t ws_size,
                              hipStream_t stream)
{
    const float* mels = (const float*)d_in[0];
    const int*   ids  = (const int*)  d_in[1];
    const float* c1w  = (const float*)d_in[2];
    const float* c1b  = (const float*)d_in[3];
    const float* c2w  = (const float*)d_in[4];
    const float* c2b  = (const float*)d_in[5];
    const float* eqw  = (const float*)d_in[6];
    const float* eqb  = (const float*)d_in[7];
    const float* ekw  = (const float*)d_in[8];
    const float* ekb  = (const float*)d_in[9];
    const float* evw  = (const float*)d_in[10];
    const float* evb  = (const float*)d_in[11];
    const float* eow  = (const float*)d_in[12];
    const float* eob  = (const float*)d_in[13];
    const float* efcw = (const float*)d_in[14];
    const float* efcb = (const float*)d_in[15];
    const float* epjw = (const float*)d_in[16];
    const float* epjb = (const float*)d_in[17];
    const float* sqw  = (const float*)d_in[18];
    const float* sqb  = (const float*)d_in[19];
    const float* skw  = (const float*)d_in[20];
    const float* skb  = (const float*)d_in[21];
    const float* svw  = (const float*)d_in[22];
    const float* svb  = (const float*)d_in[23];
    const float* soww = (const float*)d_in[24];
    const float* sob  = (const float*)d_in[25];
    const float* cqw  = (const float*)d_in[26];
    const float* cqb  = (const float*)d_in[27];
    const float* ckw  = (const float*)d_in[28];
    const float* ckb  = (const float*)d_in[29];
    const float* cvw  = (const float*)d_in[30];
    const float* cvb  = (const float*)d_in[31];
    const float* coww = (const float*)d_in[32];
    const float* cob  = (const float*)d_in[33];
    const float* fcw  = (const float*)d_in[34];
    const float* fcb  = (const float*)d_in[35];
    const float* pjw  = (const float*)d_in[36];
    const float* pjb  = (const float*)d_in[37];
    const float* embw = (const float*)d_in[38];
    const float* pose = (const float*)d_in[39];
    float* out = (float*)d_out;

    float* ws = (float*)d_ws;
    long off = 0;
    auto alloc = [&](long n) { float* p = ws + off; off += n; return p; };
    float* melsT = alloc((long)NB * TP * NM);   // [0,        480640)
    float* x1t   = alloc((long)NB * TP * NE);   // dead after conv2
    float* w1r   = alloc(3L * NE * NM);
    float* w2r   = alloc(3L * NE * NE);
    float* xenc  = alloc((long)NB * TA * NE);   // dead after cross-KV
    float* hbuf  = alloc((long)NB * TA * NE);
    float* qbuf  = alloc((long)NB * TA * NE);
    float* kbuf  = alloc((long)NB * TA * NE);
    float* vbuf  = alloc((long)NB * TA * NE);
    float* obuf  = alloc((long)NB * TA * NE);
    float* fcbuf = alloc((long)NB * TA * 2048); // ends at float 19,826,048
    float* sc    = alloc((long)NB * DHN * LQ * TA); // [19826048, 41330048)
    float* audk  = alloc((long)NB * TA * NE);
    float* audv  = alloc((long)NB * TA * NE);
    float* ctx   = alloc((long)NB * LQ * NE);
    float* q0r   = alloc((long)LQ * NE);
    float* qh    = alloc((long)NB * LQ * NE);
    float* kh    = alloc((long)NB * LQ * NE);
    float* vh    = alloc((long)NB * LQ * NE);
    float* res   = alloc((long)NB * LQ * NE);
    float* t1    = alloc((long)NB * LQ * NE);
    float* odec  = alloc((long)NB * LQ * NE);
    float* ctab  = alloc((long)LQ * 16);
    float* stab  = alloc((long)LQ * 16);
    (void)ws_size; (void)in_sizes; (void)n_in; (void)out_size;

    // --- split-scratch aliasing (no extra ws footprint) ---
    // embsp: OV*NE elems hi+lo = 26,574,848 floats at ws[0] — written ONLY at logits
    //        time; overlays melsT..fcbuf (all dead) + first 6.75M floats of sc (dead).
    // asp:   activation split, 6,144,000 elems hi+lo, at ws[26,574,848] (inside sc).
    //        Written between attention phases only; every clobber by sc occurs after
    //        its consumer GEMM has run (stream-ordered).
    // bsp:   weight split (<=2048*512 elems), at ws[32,718,848] (inside sc). Same rule.
    const long EMW = (long)OV * NE;               // 26,574,848
    unsigned short* embsp = (unsigned short*)ws;
    unsigned short* asp   = (unsigned short*)(ws + EMW);
    unsigned short* bsp   = (unsigned short*)(ws + EMW + 6144000L);

    auto split = [&](const float* x, long n, unsigned short* dst) {
        k_split<<<dim3((unsigned)CDIV(n / 4, 256)), 256, 0, stream>>>(x, dst, dst + n, n / 4);
    };
    auto gemm_mf = [&](const unsigned short* as, long nA, const unsigned short* bs, long nB,
                       const float* bias, float* Cp, int M, int N, int K, int ldc,
                       float beta, int act) {
        dim3 g(CDIV(N, 128), CDIV(M, 128));
        k_gemm_mf<<<g, 256, 0, stream>>>(as, as + nA, bs, bs + nB, bias, Cp,
                                         M, N, K, ldc, beta, act);
    };

    const int MA = NB * TA;  // 3000 encoder rows
    const int MD = NB * LQ;  // 1792 decoder rows
    const float dscale = 0.17677669529663687f; // 1/sqrt(32)
    const long nW = (long)NE * NE;       // 262,144
    const long nFC = 2048L * NE;         // 1,048,576

    // ---- conv front-end (fp32 path; K=80 not a multiple of 64) ----
    k_transpose_mels<<<CDIV((long)NB * TP * NM, 256), 256, 0, stream>>>(mels, melsT);
    k_repack_w<<<CDIV(3L * NE * NM, 256), 256, 0, stream>>>(c1w, w1r, NE, NM);
    k_repack_w<<<CDIV(3L * NE * NE, 256), 256, 0, stream>>>(c2w, w2r, NE, NE);
    k_zero_x1t_pads<<<CDIV(NB * 2 * NE, 256), 256, 0, stream>>>(x1t);
    for (int kk = 0; kk < 3; kk++) {
        bool last = (kk == 2);
        gemm(stream, true, melsT + kk * NM, w1r + (long)kk * NE * NM,
             last ? c1b : nullptr, x1t + NE,
             TMl, NE, NM, NM, NM, NE,
             (long)TP * NM, 0, 0, 0, (long)TP * NE, 0,
             NB, 1, 1.f, kk ? 1.f : 0.f, last ? 1 : 0);
    }
    for (int kk = 0; kk < 3; kk++) {
        bool last = (kk == 2);
        gemm(stream, true, x1t + kk * NE, w2r + (long)kk * NE * NE,
             last ? c2b : nullptr, xenc,
             TA, NE, NE, 2 * NE, NE, NE,
             (long)TP * NE, 0, 0, 0, (long)TA * NE, 0,
             NB, 1, 1.f, kk ? 1.f : 0.f, last ? 1 : 0);
    }
    k_add_encpos<<<CDIV((long)NB * TA * NE, 256), 256, 0, stream>>>(xenc);

    // ---- encoder layers ----
    for (int l = 0; l < 2; l++) {
        const float* qw = eqw + (long)l * NE * NE; const float* qb = eqb + l * NE;
        const float* kw = ekw + (long)l * NE * NE; const float* kb = ekb + l * NE;
        const float* vw = evw + (long)l * NE * NE; const float* vb = evb + l * NE;
        const float* ow = eow + (long)l * NE * NE; const float* ob = eob + l * NE;
        const float* fw = efcw + (long)l * 2048 * NE; const float* fb = efcb + l * 2048;
        const float* pw = epjw + (long)l * NE * 2048; const float* pb = epjb + l * NE;

        k_rms512<<<CDIV(MA, 4), 256, 0, stream>>>(xenc, hbuf, MA);
        split(hbuf, (long)MA * NE, asp);
        split(qw, nW, bsp);
        gemm_mf(asp, (long)MA * NE, bsp, nW, qb, qbuf, MA, NE, NE, NE, 0.f, 0);
        split(kw, nW, bsp);
        gemm_mf(asp, (long)MA * NE, bsp, nW, kb, kbuf, MA, NE, NE, NE, 0.f, 0);
        split(vw, nW, bsp);
        gemm_mf(asp, (long)MA * NE, bsp, nW, vb, vbuf, MA, NE, NE, NE, 0.f, 0);
        k_rms_heads<64><<<CDIV((long)MA * EH, 4), 256, 0, stream>>>(qbuf, (long)MA * EH);
        k_rms_heads<64><<<CDIV((long)MA * EH, 4), 256, 0, stream>>>(kbuf, (long)MA * EH);
        gemm(stream, true, qbuf, kbuf, nullptr, sc, TA, TA, EHD, NE, NE, TA,
             (long)TA * NE, EHD, (long)TA * NE, EHD, (long)EH * TA * TA, (long)TA * TA,
             NB * EH, EH, 0.125f, 0.f, 0);
        k_softmax<<<CDIV((long)NB * EH * TA, 4), 256, 0, stream>>>(sc, EH, TA, TA, 0, nullptr, (long)NB * EH * TA);
        gemm(stream, false, sc, vbuf, nullptr, obuf, TA, EHD, TA, TA, NE, NE,
             (long)EH * TA * TA, (long)TA * TA, (long)TA * NE, EHD, (long)TA * NE, EHD,
             NB * EH, EH, 1.f, 0.f, 0);
        k_decorrelate<64><<<CDIV((long)MA * EH, 4), 256, 0, stream>>>(obuf, vbuf, (long)MA * EH);
        split(obuf, (long)MA * NE, asp);
        split(ow, nW, bsp);
        gemm_mf(asp, (long)MA * NE, bsp, nW, ob, xenc, MA, NE, NE, NE, 1.f, 0);

        k_rms512<<<CDIV(MA, 4), 256, 0, stream>>>(xenc, hbuf, MA);
        split(hbuf, (long)MA * NE, asp);
        split(fw, nFC, bsp);
        gemm_mf(asp, (long)MA * NE, bsp, nFC, fb, fcbuf, MA, 2048, NE, 2048, 0.f, 1);
        split(fcbuf, (long)MA * 2048, asp);
        split(pw, nFC, bsp);
        gemm_mf(asp, (long)MA * 2048, bsp, nFC, pb, xenc, MA, NE, 2048, NE, 1.f, 0);
    }

    // ---- cross K/V from encoder output ----
    k_rms512<<<CDIV(MA, 4), 256, 0, stream>>>(xenc, hbuf, MA);
    split(hbuf, (long)MA * NE, asp);
    split(ckw, nW, bsp);
    gemm_mf(asp, (long)MA * NE, bsp, nW, ckb, audk, MA, NE, NE, NE, 0.f, 0);
    k_rms_heads<32><<<CDIV((long)MA * DHN, 8), 256, 0, stream>>>(audk, (long)MA * DHN);
    split(cvw, nW, bsp);
    gemm_mf(asp, (long)MA * NE, bsp, nW, cvb, audv, MA, NE, NE, NE, 0.f, 0);

    // ---- decoder ----
    k_embed<<<CDIV((long)NB * LQ * NE, 256), 256, 0, stream>>>(ids, embw, pose, ctx);
    k_rms512<<<CDIV(MD, 4), 256, 0, stream>>>(ctx, ctx, MD);
    k_ropetab<<<CDIV(LQ * 16, 256), 256, 0, stream>>>(ctab, stab);

    k_bcast_pos<<<CDIV((long)LQ * NE, 256), 256, 0, stream>>>(pose, q0r, 1);
    k_rms512<<<CDIV(LQ, 4), 256, 0, stream>>>(q0r, q0r, LQ);
    split(q0r, (long)LQ * NE, asp);
    split(sqw, nW, bsp);
    gemm_mf(asp, (long)LQ * NE, bsp, nW, sqb, qh, LQ, NE, NE, NE, 0.f, 0);
    k_rope<<<CDIV((long)LQ * DHN * 16, 256), 256, 0, stream>>>(qh, 1, 0, ctab, stab);
    k_rms_heads<32><<<CDIV((long)LQ * DHN, 8), 256, 0, stream>>>(qh, (long)LQ * DHN);

    split(ctx, (long)MD * NE, asp);
    split(skw, nW, bsp);
    gemm_mf(asp, (long)MD * NE, bsp, nW, skb, kh, MD, NE, NE, NE, 0.f, 0);
    k_rope<<<CDIV((long)NB * LQ * DHN * 16, 256), 256, 0, stream>>>(kh, NB, 1, ctab, stab);
    k_rms_heads<32><<<CDIV((long)MD * DHN, 8), 256, 0, stream>>>(kh, (long)MD * DHN);
    split(svw, nW, bsp);
    gemm_mf(asp, (long)MD * NE, bsp, nW, svb, vh, MD, NE, NE, NE, 0.f, 0);

    // self-attention (fp32 path; qh shared across batch: sAb = 0)
    gemm(stream, true, qh, kh, nullptr, sc, LQ, LQ, HDD, NE, NE, LQ,
         0, HDD, (long)LQ * NE, HDD, (long)DHN * LQ * LQ, (long)LQ * LQ,
         NB * DHN, DHN, dscale, 0.f, 0);
    k_softmax<<<CDIV((long)NB * DHN * LQ, 4), 256, 0, stream>>>(sc, DHN, LQ, LQ, 1, ids, (long)NB * DHN * LQ);
    gemm(stream, false, sc, vh, nullptr, odec, LQ, HDD, LQ, LQ, NE, NE,
         (long)DHN * LQ * LQ, (long)LQ * LQ, (long)LQ * NE, HDD, (long)LQ * NE, HDD,
         NB * DHN, DHN, 1.f, 0.f, 0);
    k_decorrelate<32><<<CDIV((long)MD * DHN, 8), 256, 0, stream>>>(odec, vh, (long)MD * DHN);
    k_bcast_pos<<<CDIV((long)NB * LQ * NE, 256), 256, 0, stream>>>(pose, res, NB);
    split(odec, (long)MD * NE, asp);
    split(soww, nW, bsp);
    gemm_mf(asp, (long)MD * NE, bsp, nW, sob, res, MD, NE, NE, NE, 1.f, 0);

    // cross-attention
    k_rms512<<<CDIV(MD, 4), 256, 0, stream>>>(res, t1, MD);
    split(t1, (long)MD * NE, asp);
    split(cqw, nW, bsp);
    gemm_mf(asp, (long)MD * NE, bsp, nW, cqb, qh, MD, NE, NE, NE, 0.f, 0);
    k_rope<<<CDIV((long)NB * LQ * DHN * 16, 256), 256, 0, stream>>>(qh, NB, 0, ctab, stab);
    k_rms_heads<32><<<CDIV((long)MD * DHN, 8), 256, 0, stream>>>(qh, (long)MD * DHN);
    gemm(stream, true, qh, audk, nullptr, sc, LQ, TA, HDD, NE, NE, TA,
         (long)LQ * NE, HDD, (long)TA * NE, HDD, (long)DHN * LQ * TA, (long)LQ * TA,
         NB * DHN, DHN, dscale, 0.f, 0);
    k_softmax<<<CDIV((long)NB * DHN * LQ, 4), 256, 0, stream>>>(sc, DHN, LQ, TA, 0, nullptr, (long)NB * DHN * LQ);
    gemm(stream, false, sc, audv, nullptr, odec, LQ, HDD, TA, TA, NE, NE,
         (long)DHN * LQ * TA, (long)LQ * TA, (long)TA * NE, HDD, (long)LQ * NE, HDD,
         NB * DHN, DHN, 1.f, 0.f, 0);
    split(odec, (long)MD * NE, asp);
    split(coww, nW, bsp);
    gemm_mf(asp, (long)MD * NE, bsp, nW, cob, res, MD, NE, NE, NE, 1.f, 0);

    // decoder MLP
    k_rms512<<<CDIV(MD, 4), 256, 0, stream>>>(res, t1, MD);
    split(t1, (long)MD * NE, asp);
    split(fcw, nFC, bsp);
    gemm_mf(asp, (long)MD * NE, bsp, nFC, fcb, fcbuf, MD, 2048, NE, 2048, 0.f, 1);
    split(fcbuf, (long)MD * 2048, asp);
    split(pjw, nFC, bsp);
    gemm_mf(asp, (long)MD * 2048, bsp, nFC, pjb, res, MD, NE, 2048, NE, 1.f, 0);

    // logits: B = embw split overlays dead ws[0 .. 26.57M floats)
    k_rms512<<<CDIV(MD, 4), 256, 0, stream>>>(res, t1, MD);
    split(t1, (long)MD * NE, asp);
    split(embw, EMW, embsp);
    gemm_mf(asp, (long)MD * NE, embsp, EMW, nullptr, out, MD, OV, NE, OV, 0.f, 0);
}

// Round 2
// 3213.751 us; speedup vs baseline: 1.7945x; 1.1061x over previous
//
#include <hip/hip_runtime.h>
#include <math.h>

#define CDIV(a,b) (((a)+(b)-1)/(b))

static constexpr int NE  = 512;   // n_embed
static constexpr int EH  = 8;     // encoder heads
static constexpr int EHD = 64;    // encoder head dim
static constexpr int DHN = 16;    // decoder heads
static constexpr int HDD = 32;    // decoder head dim
static constexpr int NM  = 80;    // mels
static constexpr int TMl = 1500;  // mel time
static constexpr int TP  = 1502;  // padded time
static constexpr int TA  = 750;   // audio ctx
static constexpr int LQ  = 448;   // text ctx
static constexpr int NB  = 4;     // batch
static constexpr int OV  = 51904; // padded vocab

typedef __attribute__((ext_vector_type(8))) short bf16x8;
typedef __attribute__((ext_vector_type(8))) unsigned short us8;
typedef __attribute__((ext_vector_type(4))) float f32x4;

// ---------------- elementwise / layout kernels ----------------

__global__ void k_transpose_mels(const float* __restrict__ mels, float* __restrict__ melsT) {
    long idx = (long)blockIdx.x * blockDim.x + threadIdx.x;
    long total = (long)NB * TP * NM;
    if (idx >= total) return;
    int ci = (int)(idx % NM);
    int t  = (int)((idx / NM) % TP);
    int b  = (int)(idx / ((long)NM * TP));
    float v = 0.f;
    if (t >= 1 && t <= TMl) v = mels[((long)b * NM + ci) * TMl + (t - 1)];
    melsT[idx] = v;
}

__global__ void k_zero_x1t_pads(float* __restrict__ x1t) {
    int idx = blockIdx.x * blockDim.x + threadIdx.x;
    if (idx >= NB * 2 * NE) return;
    int c = idx % NE;
    int r = (idx / NE) % 2;
    int b = idx / (NE * 2);
    int t = r ? (TP - 1) : 0;
    x1t[((long)b * TP + t) * NE + c] = 0.f;
}

__global__ void k_repack_w(const float* __restrict__ w, float* __restrict__ wr, int O, int I) {
    // w[o][i][k] -> wr[o][k*I + i]   (taps stacked along K: row o has 3*I contiguous)
    long idx = (long)blockIdx.x * blockDim.x + threadIdx.x;
    long total = (long)O * I * 3;
    if (idx >= total) return;
    int k = (int)(idx % 3);
    int i = (int)((idx / 3) % I);
    int o = (int)(idx / ((long)3 * I));
    wr[(long)o * (3 * I) + k * I + i] = w[idx];
}

__global__ void k_add_encpos(float* __restrict__ x) {
    long idx = (long)blockIdx.x * blockDim.x + threadIdx.x;
    long total = (long)NB * TA * NE;
    if (idx >= total) return;
    int c = (int)(idx % NE);
    int t = (int)((idx / NE) % TA);
    double inc = log(10000.0) / 255.0;
    int j = c & 255;
    double st = (double)t * exp(-inc * (double)j);
    float p = (c < 256) ? (float)sin(st) : (float)cos(st);
    x[idx] += p;
}

__global__ void k_embed(const int* __restrict__ ids, const float* __restrict__ ew,
                        const float* __restrict__ pos, float* __restrict__ ctx) {
    long idx = (long)blockIdx.x * blockDim.x + threadIdx.x;
    long total = (long)NB * LQ * NE;
    if (idx >= total) return;
    int c = (int)(idx % NE);
    int t = (int)((idx / NE) % LQ);
    int b = (int)(idx / ((long)NE * LQ));
    int id = ids[b * LQ + t];
    float v = ew[(long)id * NE + c] * 22.62741699796952f;
    if (t >= 1) v += pos[(long)(t - 1) * NE + c];
    ctx[idx] = v;
}

__global__ void k_bcast_pos(const float* __restrict__ pos, float* __restrict__ dst, int Bn) {
    long idx = (long)blockIdx.x * blockDim.x + threadIdx.x;
    long total = (long)Bn * LQ * NE;
    if (idx >= total) return;
    int c = (int)(idx % NE);
    int t = (int)((idx / NE) % LQ);
    dst[idx] = pos[(long)t * NE + c];
}

__global__ void k_ropetab(float* __restrict__ ctab, float* __restrict__ stab) {
    int idx = blockIdx.x * blockDim.x + threadIdx.x;
    if (idx >= LQ * 16) return;
    int m = idx % 16;
    int t = idx / 16;
    double inv = pow(10000.0, -(double)(2 * m) / 32.0);
    double f = (double)t * inv;
    ctab[idx] = (float)cos(f);
    stab[idx] = (float)sin(f);
}

// x rows are (b, t); head h lives at column h*HDD within a row of stride RS.
__global__ void k_rope(float* __restrict__ x, int Bn, int shiftK, int RS,
                       const float* __restrict__ ctab, const float* __restrict__ stab) {
    long idx = (long)blockIdx.x * blockDim.x + threadIdx.x;
    long total = (long)Bn * LQ * DHN * 16;
    if (idx >= total) return;
    int m = (int)(idx % 16);
    int h = (int)((idx / 16) % DHN);
    int t = (int)((idx / (16 * DHN)) % LQ);
    int b = (int)(idx / ((long)16 * DHN * LQ));
    int tt = shiftK ? (t > 0 ? t - 1 : 0) : t;
    float c = ctab[tt * 16 + m];
    float s = stab[tt * 16 + m];
    long base = ((long)b * LQ + t) * RS + h * HDD;
    float x1 = x[base + m];
    float x2 = x[base + 16 + m];
    x[base + m]      = x1 * c + x2 * s;
    x[base + 16 + m] = -x1 * s + x2 * c;
}

// ---------------- rms / decorrelate / softmax ----------------

__global__ void k_rms512(const float* __restrict__ src, float* __restrict__ dst, int rows) {
    int wave = blockIdx.x * (blockDim.x >> 6) + (threadIdx.x >> 6);
    int lane = threadIdx.x & 63;
    if (wave >= rows) return;
    const float* s = src + (long)wave * NE;
    float4 a = *(const float4*)(s + lane * 4);
    float4 b = *(const float4*)(s + 256 + lane * 4);
    float ss = a.x*a.x + a.y*a.y + a.z*a.z + a.w*a.w
             + b.x*b.x + b.y*b.y + b.z*b.z + b.w*b.w;
    for (int m = 32; m >= 1; m >>= 1) ss += __shfl_xor(ss, m, 64);
    float sc = rsqrtf(ss / 512.f + 1e-6f);
    float* d = dst + (long)wave * NE;
    a.x *= sc; a.y *= sc; a.z *= sc; a.w *= sc;
    b.x *= sc; b.y *= sc; b.z *= sc; b.w *= sc;
    *(float4*)(d + lane * 4) = a;
    *(float4*)(d + 256 + lane * 4) = b;
}

// generalized: chunk rr -> t = rr/CU, c = rr%CU, base = t*RS + c*D
template<int D>
__global__ void k_rms_heads(float* __restrict__ x, long nchunks, int CU, int RS) {
    const int RPW = 64 / D;
    long wave = (long)blockIdx.x * (blockDim.x >> 6) + (threadIdx.x >> 6);
    int lane = threadIdx.x & 63;
    long rr = wave * RPW + lane / D;
    if (rr >= nchunks) return;
    int col = lane % D;
    long idx = (rr / CU) * (long)RS + (rr % CU) * D + col;
    float v = x[idx];
    float ss = v * v;
    for (int m = D / 2; m >= 1; m >>= 1) ss += __shfl_xor(ss, m, 64);
    x[idx] = v * rsqrtf(ss / (float)D + 1e-6f);
}

// o packed [nchunks][D]; v strided: (rr/CU)*vRS + vOff + (rr%CU)*D
template<int D>
__global__ void k_decorrelate(float* __restrict__ o, const float* __restrict__ v,
                              long nchunks, int CU, int vRS, int vOff) {
    const int RPW = 64 / D;
    long wave = (long)blockIdx.x * (blockDim.x >> 6) + (threadIdx.x >> 6);
    int lane = threadIdx.x & 63;
    long rr = wave * RPW + lane / D;
    if (rr >= nchunks) return;
    int col = lane % D;
    long oidx = rr * D + col;
    long vidx = (rr / CU) * (long)vRS + vOff + (rr % CU) * D + col;
    float ov = o[oidx];
    float vv = v[vidx];
    float dov = ov * vv;
    float dvv = vv * vv;
    for (int m = D / 2; m >= 1; m >>= 1) {
        dov += __shfl_xor(dov, m, 64);
        dvv += __shfl_xor(dvv, m, 64);
    }
    float nv = sqrtf(dvv);
    float c = fmaxf(nv, 1e-9f);
    o[oidx] = ov - (dov / (c * c)) * vv;
}

__global__ void k_softmax(float* __restrict__ s, int H, int Lq, int Lk,
                          int causal, const int* __restrict__ ids, long nrows) {
    long row = (long)blockIdx.x * (blockDim.x >> 6) + (threadIdx.x >> 6);
    if (row >= nrows) return;
    int lane = threadIdx.x & 63;
    int qt = (int)(row % Lq);
    long z = row / Lq;
    int b = (int)(z / H);
    float* p = s + row * (long)Lk;
    int cnt = (Lk + 63) >> 6;
    float vals[12];
    float mx = -INFINITY;
    for (int i = 0; i < cnt; i++) {
        int k = lane + (i << 6);
        float v = -INFINITY;
        if (k < Lk) {
            v = p[k];
            if (causal && k > qt) v = -INFINITY;
            if (ids && ids[(long)b * Lk + k] == 0) v = -INFINITY;
        }
        vals[i] = v;
        mx = fmaxf(mx, v);
    }
    for (int m = 32; m >= 1; m >>= 1) mx = fmaxf(mx, __shfl_xor(mx, m, 64));
    float sum = 0.f;
    for (int i = 0; i < cnt; i++) {
        float e = expf(vals[i] - mx);
        vals[i] = e;
        sum += e;
    }
    for (int m = 32; m >= 1; m >>= 1) sum += __shfl_xor(sum, m, 64);
    float inv = 1.f / sum;
    for (int i = 0; i < cnt; i++) {
        int k = lane + (i << 6);
        if (k < Lk) p[k] = vals[i] * inv;
    }
}

// ---------------- fp32 batched GEMM (PV only) ----------------

template<bool TRANSB>
__global__ __launch_bounds__(256) void k_gemm(
    const float* __restrict__ A, const float* __restrict__ Bm,
    const float* __restrict__ bias, float* __restrict__ C,
    int M, int N, int K, int lda, int ldb, int ldc,
    long sAb, long sAh, long sBb, long sBh, long sCb, long sCh, int H,
    float alpha, float beta, int act)
{
    __shared__ __align__(16) float As[16][68];
    __shared__ __align__(16) float Bs[16][68];
    int z = blockIdx.z;
    int bb = z / H, hh = z % H;
    A  += (long)bb * sAb + (long)hh * sAh;
    Bm += (long)bb * sBb + (long)hh * sBh;
    C  += (long)bb * sCb + (long)hh * sCh;
    int m0 = blockIdx.y * 64, n0 = blockIdx.x * 64;
    int tid = threadIdx.x;
    int tm0 = (tid / 16) * 4, tn0 = (tid % 16) * 4;
    float acc[4][4] = {};
    for (int k0 = 0; k0 < K; k0 += 16) {
        {
            int k = tid & 15, mr = tid >> 4;
            #pragma unroll
            for (int i = 0; i < 4; i++) {
                int m = mr + i * 16;
                float v = 0.f;
                if (m0 + m < M && k0 + k < K) v = A[(long)(m0 + m) * lda + k0 + k];
                As[k][m] = v;
            }
            if (TRANSB) {
                #pragma unroll
                for (int i = 0; i < 4; i++) {
                    int n = mr + i * 16;
                    float v = 0.f;
                    if (n0 + n < N && k0 + k < K) v = Bm[(long)(n0 + n) * ldb + k0 + k];
                    Bs[k][n] = v;
                }
            } else {
                int n = tid & 63, kr = tid >> 6;
                #pragma unroll
                for (int i = 0; i < 4; i++) {
                    int k2 = kr + i * 4;
                    float v = 0.f;
                    if (k0 + k2 < K && n0 + n < N) v = Bm[(long)(k0 + k2) * ldb + n0 + n];
                    Bs[k2][n] = v;
                }
            }
        }
        __syncthreads();
        #pragma unroll
        for (int kk = 0; kk < 16; kk++) {
            float4 av = *(const float4*)&As[kk][tm0];
            float4 bv = *(const float4*)&Bs[kk][tn0];
            float aa[4] = {av.x, av.y, av.z, av.w};
            float bbv[4] = {bv.x, bv.y, bv.z, bv.w};
            #pragma unroll
            for (int i = 0; i < 4; i++)
                #pragma unroll
                for (int j = 0; j < 4; j++)
                    acc[i][j] += aa[i] * bbv[j];
        }
        __syncthreads();
    }
    #pragma unroll
    for (int i = 0; i < 4; i++) {
        int m = m0 + tm0 + i;
        if (m >= M) continue;
        #pragma unroll
        for (int j = 0; j < 4; j++) {
            int n = n0 + tn0 + j;
            if (n >= N) continue;
            float v = alpha * acc[i][j];
            if (bias) v += bias[n];
            long off = (long)m * ldc + n;
            if (beta != 0.f) v += beta * C[off];
            if (act) v = 0.5f * v * (1.f + erff(v * 0.70710678118654752f));
            C[off] = v;
        }
    }
}

static inline void gemm(hipStream_t st, bool tb, const float* A, const float* Bm,
                        const float* bias, float* C, int M, int N, int K,
                        int lda, int ldb, int ldc,
                        long sAb, long sAh, long sBb, long sBh, long sCb, long sCh,
                        int Z, int H, float alpha, float beta, int act)
{
    dim3 g(CDIV(N, 64), CDIV(M, 64), Z), blk(256);
    if (tb) k_gemm<true ><<<g, blk, 0, st>>>(A, Bm, bias, C, M, N, K, lda, ldb, ldc,
                                             sAb, sAh, sBb, sBh, sCb, sCh, H, alpha, beta, act);
    else    k_gemm<false><<<g, blk, 0, st>>>(A, Bm, bias, C, M, N, K, lda, ldb, ldc,
                                             sAb, sAh, sBb, sBh, sCb, sCh, H, alpha, beta, act);
}

// ---------------- MFMA GEMM with fused bf16 hi/lo split ----------------
// C = act(alpha * A(M,K) . B(N,K)^T + bias + beta*C), batched via z = bb*H + hh.
// Sources are fp32; staging converts to hi/lo bf16 in-register (Ootomo bf16x3:
// hh + hl + lh passes; dropped al*bl <= 2^-16 relative -> fp32-level accuracy).
// 128x128 tile, BK=32, 4 waves (2x2 of 64x64), 32 KB LDS -> 4 blocks/CU.
// LDS planes Ah/Al/Bh/Bl of [128 rows][4 slots of 16B], slot = g ^ ((r>>1)&3)
// -> quarter-wave 2-way on both ds_write_b128 and ds_read_b128 (free).
// XCD-bijective block remap, m-fastest within each XCD chunk (B-panel L2 reuse).
// Requires K % 8 == 0; lda/ldb multiples of 4; A/B 16B-aligned.

__global__ __launch_bounds__(256, 4) void k_gemm_mf(
    const float* __restrict__ A, const float* __restrict__ B,
    const float* __restrict__ bias, float* __restrict__ C,
    int M, int N, int K, int lda, int ldb, int ldc,
    long sAb, long sAh, long sBb, long sBh, long sCb, long sCh, int H,
    int gx, int gy, float alpha, float beta, int act)
{
    __shared__ __align__(16) unsigned short lds[16384]; // 32 KB: Ah,Al,Bh,Bl
    // ---- XCD-bijective remap, m-fastest ----
    int nwg = gridDim.x;
    int flat = blockIdx.x;
    int q8 = nwg >> 3, r8 = nwg & 7;
    int xcd = flat & 7, idx = flat >> 3;
    int wg = (xcd < r8 ? xcd * (q8 + 1) : r8 * (q8 + 1) + (xcd - r8) * q8) + idx;
    int my = wg % gy;
    int t2 = wg / gy;
    int nx = t2 % gx;
    int z  = t2 / gx;
    int bb = z / H, hh = z % H;
    A += (long)bb * sAb + (long)hh * sAh;
    B += (long)bb * sBb + (long)hh * sBh;
    C += (long)bb * sCb + (long)hh * sCh;
    int m0 = my * 128, n0 = nx * 128;
    const int tid = threadIdx.x;
    const int wid = tid >> 6, lane = tid & 63;
    const int wm = wid >> 1, wn = wid & 1;
    const int lr = lane & 15, lk = lane >> 4;
    const int rA = tid >> 2, g = tid & 3;

    f32x4 acc[4][4] = {};

    for (int k0 = 0; k0 < K; k0 += 32) {
        __syncthreads();
        int kk = k0 + g * 8;
        bool kv = kk < K;
        #pragma unroll
        for (int half = 0; half < 2; ++half) {
            int r = rA + half * 64;
            int off = r * 32 + (g ^ ((r >> 1) & 3)) * 8;
            {
                float4 f0 = {0,0,0,0}, f1 = {0,0,0,0};
                if (kv && m0 + r < M) {
                    const float* p = A + (long)(m0 + r) * lda + kk;
                    f0 = *(const float4*)p;
                    f1 = *(const float4*)(p + 4);
                }
                float ff[8] = {f0.x,f0.y,f0.z,f0.w,f1.x,f1.y,f1.z,f1.w};
                us8 h, l;
                #pragma unroll
                for (int j = 0; j < 8; ++j) {
                    unsigned bu = __float_as_uint(ff[j]);
                    unsigned hb = bu & 0xffff0000u;
                    h[j] = (unsigned short)(hb >> 16);
                    l[j] = (unsigned short)(__float_as_uint(ff[j] - __uint_as_float(hb)) >> 16);
                }
                *(us8*)(lds + off) = h;
                *(us8*)(lds + 4096 + off) = l;
            }
            {
                float4 f0 = {0,0,0,0}, f1 = {0,0,0,0};
                if (kv && n0 + r < N) {
                    const float* p = B + (long)(n0 + r) * ldb + kk;
                    f0 = *(const float4*)p;
                    f1 = *(const float4*)(p + 4);
                }
                float ff[8] = {f0.x,f0.y,f0.z,f0.w,f1.x,f1.y,f1.z,f1.w};
                us8 h, l;
                #pragma unroll
                for (int j = 0; j < 8; ++j) {
                    unsigned bu = __float_as_uint(ff[j]);
                    unsigned hb = bu & 0xffff0000u;
                    h[j] = (unsigned short)(hb >> 16);
                    l[j] = (unsigned short)(__float_as_uint(ff[j] - __uint_as_float(hb)) >> 16);
                }
                *(us8*)(lds + 8192 + off) = h;
                *(us8*)(lds + 12288 + off) = l;
            }
        }
        __syncthreads();
        bf16x8 ah[4], al[4];
        #pragma unroll
        for (int i = 0; i < 4; ++i) {
            int ra = wm * 64 + i * 16 + lr;
            int ao = ra * 32 + (lk ^ ((ra >> 1) & 3)) * 8;
            ah[i] = *(const bf16x8*)(lds + ao);
            al[i] = *(const bf16x8*)(lds + 4096 + ao);
        }
        #pragma unroll
        for (int j = 0; j < 4; ++j) {
            int rb = wn * 64 + j * 16 + lr;
            int bo = rb * 32 + (lk ^ ((rb >> 1) & 3)) * 8;
            bf16x8 bh = *(const bf16x8*)(lds + 8192 + bo);
            bf16x8 bl = *(const bf16x8*)(lds + 12288 + bo);
            #pragma unroll
            for (int i = 0; i < 4; ++i) {
                acc[i][j] = __builtin_amdgcn_mfma_f32_16x16x32_bf16(ah[i], bh, acc[i][j], 0, 0, 0);
                acc[i][j] = __builtin_amdgcn_mfma_f32_16x16x32_bf16(ah[i], bl, acc[i][j], 0, 0, 0);
                acc[i][j] = __builtin_amdgcn_mfma_f32_16x16x32_bf16(al[i], bh, acc[i][j], 0, 0, 0);
            }
        }
    }
    // epilogue: C/D layout col = lane&15, row = (lane>>4)*4 + reg  [m89-verified]
    #pragma unroll
    for (int i = 0; i < 4; ++i) {
        int rowb = m0 + wm * 64 + i * 16 + lk * 4;
        #pragma unroll
        for (int j = 0; j < 4; ++j) {
            int col = n0 + wn * 64 + j * 16 + lr;
            if (col >= N) continue;
            float bi = bias ? bias[col] : 0.f;
            #pragma unroll
            for (int qi = 0; qi < 4; ++qi) {
                int row = rowb + qi;
                if (row >= M) continue;
                float v = alpha * acc[i][j][qi] + bi;
                long off = (long)row * ldc + col;
                if (beta != 0.f) v += beta * C[off];
                if (act) v = 0.5f * v * (1.f + erff(v * 0.70710678118654752f));
                C[off] = v;
            }
        }
    }
}

static inline void gemm_mf(hipStream_t st, const float* A, const float* B, const float* bias,
                           float* C, int M, int N, int K, int lda, int ldb, int ldc,
                           long sAb, long sAh, long sBb, long sBh, long sCb, long sCh,
                           int Z, int H, float alpha, float beta, int act)
{
    int gx = CDIV(N, 128), gy = CDIV(M, 128);
    dim3 g((unsigned)(gx * gy * Z));
    k_gemm_mf<<<g, 256, 0, st>>>(A, B, bias, C, M, N, K, lda, ldb, ldc,
                                 sAb, sAh, sBb, sBh, sCb, sCh, H, gx, gy, alpha, beta, act);
}

// ---------------- launcher ----------------

extern "C" void kernel_launch(void* const* d_in, const int* in_sizes, int n_in,
                              void* d_out, int out_size, void* d_ws, size_t ws_size,
                              hipStream_t stream)
{
    const float* mels = (const float*)d_in[0];
    const int*   ids  = (const int*)  d_in[1];
    const float* c1w  = (const float*)d_in[2];
    const float* c1b  = (const float*)d_in[3];
    const float* c2w  = (const float*)d_in[4];
    const float* c2b  = (const float*)d_in[5];
    const float* eqw  = (const float*)d_in[6];
    const float* eqb  = (const float*)d_in[7];
    const float* ekw  = (const float*)d_in[8];
    const float* ekb  = (const float*)d_in[9];
    const float* evw  = (const float*)d_in[10];
    const float* evb  = (const float*)d_in[11];
    const float* eow  = (const float*)d_in[12];
    const float* eob  = (const float*)d_in[13];
    const float* efcw = (const float*)d_in[14];
    const float* efcb = (const float*)d_in[15];
    const float* epjw = (const float*)d_in[16];
    const float* epjb = (const float*)d_in[17];
    const float* sqw  = (const float*)d_in[18];
    const float* sqb  = (const float*)d_in[19];
    const float* skw  = (const float*)d_in[20];
    const float* skb  = (const float*)d_in[21];
    const float* svw  = (const float*)d_in[22];
    const float* svb  = (const float*)d_in[23];
    const float* soww = (const float*)d_in[24];
    const float* sob  = (const float*)d_in[25];
    const float* cqw  = (const float*)d_in[26];
    const float* cqb  = (const float*)d_in[27];
    const float* ckw  = (const float*)d_in[28];
    const float* ckb  = (const float*)d_in[29];
    const float* cvw  = (const float*)d_in[30];
    const float* cvb  = (const float*)d_in[31];
    const float* coww = (const float*)d_in[32];
    const float* cob  = (const float*)d_in[33];
    const float* fcw  = (const float*)d_in[34];
    const float* fcb  = (const float*)d_in[35];
    const float* pjw  = (const float*)d_in[36];
    const float* pjb  = (const float*)d_in[37];
    const float* embw = (const float*)d_in[38];
    const float* pose = (const float*)d_in[39];
    float* out = (float*)d_out;

    float* ws = (float*)d_ws;
    long off = 0;
    auto alloc = [&](long n) { float* p = ws + off; off += n; return p; };
    float* melsT = alloc((long)NB * TP * NM);
    float* x1t   = alloc((long)NB * TP * NE);
    float* w1r   = alloc(3L * NE * NM);     // conv1 weights, K-stacked [512][240]
    float* w2r   = alloc(3L * NE * NE);     // conv2 K-stacked [512][1536]; later wcat
    float* xenc  = alloc((long)NB * TA * NE);
    float* hbuf  = alloc((long)NB * TA * NE);
    float* qbuf  = alloc((long)NB * TA * NE);   // unused (kept for layout stability)
    float* kbuf  = alloc((long)NB * TA * NE);   // unused
    float* vbuf  = alloc((long)NB * TA * NE);   // unused
    float* obuf  = alloc((long)NB * TA * NE);
    float* fcbuf = alloc((long)NB * TA * 2048); // qkv / self-kv / cross-kv / mlp
    float* sc    = alloc((long)NB * DHN * LQ * TA);
    float* audk  = alloc((long)NB * TA * NE);   // unused
    float* audv  = alloc((long)NB * TA * NE);   // unused
    float* ctx   = alloc((long)NB * LQ * NE);
    float* q0r   = alloc((long)LQ * NE);
    float* qh    = alloc((long)NB * LQ * NE);
    float* kh    = alloc((long)NB * LQ * NE);   // unused
    float* vh    = alloc((long)NB * LQ * NE);   // unused
    float* res   = alloc((long)NB * LQ * NE);
    float* t1    = alloc((long)NB * LQ * NE);
    float* odec  = alloc((long)NB * LQ * NE);
    float* ctab  = alloc((long)LQ * 16);
    float* stab  = alloc((long)LQ * 16);
    float* cbias = alloc(2048);
    (void)ws_size; (void)in_sizes; (void)n_in; (void)out_size;
    (void)qbuf; (void)kbuf; (void)vbuf; (void)audk; (void)audv; (void)kh; (void)vh;

    const int MA = NB * TA;  // 3000 encoder rows
    const int MD = NB * LQ;  // 1792 decoder rows
    const float dscale = 0.17677669529663687f; // 1/sqrt(32)

    // fused KV regions inside fcbuf (dead outside their window; MLP overwrites later)
    float* selfkv = fcbuf;               // [1792][1024]  (kh | vh)
    float* audkv  = fcbuf + 3000000L;    // [3000][1024]  (audk | audv), 3.072M <= 3.144M

    auto dcopy = [&](float* dst, const float* src, long n) {
        hipMemcpyAsync(dst, src, n * sizeof(float), hipMemcpyDeviceToDevice, stream);
    };

    // ---- conv front-end: taps stacked along K ----
    k_transpose_mels<<<CDIV((long)NB * TP * NM, 256), 256, 0, stream>>>(mels, melsT);
    k_repack_w<<<CDIV(3L * NE * NM, 256), 256, 0, stream>>>(c1w, w1r, NE, NM);
    k_repack_w<<<CDIV(3L * NE * NE, 256), 256, 0, stream>>>(c2w, w2r, NE, NE);
    k_zero_x1t_pads<<<CDIV(NB * 2 * NE, 256), 256, 0, stream>>>(x1t);
    // conv1: out[t] = gelu(sum_{tap,i} melsT[t+tap][i] * w1r[o][tap*80+i] + b)
    gemm_mf(stream, melsT, w1r, c1b, x1t + NE,
            TMl, NE, 3 * NM, NM, 3 * NM, NE,
            (long)TP * NM, 0, 0, 0, (long)TP * NE, 0, NB, 1, 1.f, 0.f, 1);
    // conv2 (stride 2): out[t] = gelu(sum x1t[2t+tap][i] * w2r[o][tap*512+i] + b)
    gemm_mf(stream, x1t, w2r, c2b, xenc,
            TA, NE, 3 * NE, 2 * NE, 3 * NE, NE,
            (long)TP * NE, 0, 0, 0, (long)TA * NE, 0, NB, 1, 1.f, 0.f, 1);
    k_add_encpos<<<CDIV((long)NB * TA * NE, 256), 256, 0, stream>>>(xenc);

    // ---- encoder layers ----
    for (int l = 0; l < 2; l++) {
        const float* qw = eqw + (long)l * NE * NE; const float* qb = eqb + l * NE;
        const float* kw = ekw + (long)l * NE * NE; const float* kb = ekb + l * NE;
        const float* vw = evw + (long)l * NE * NE; const float* vb = evb + l * NE;
        const float* ow = eow + (long)l * NE * NE; const float* ob = eob + l * NE;
        const float* fw = efcw + (long)l * 2048 * NE; const float* fb = efcb + l * 2048;
        const float* pw = epjw + (long)l * NE * 2048; const float* pb = epjb + l * NE;

        // fused QKV: wcat = [qw; kw; vw] (1536 x 512) in w2r (dead after conv2)
        dcopy(w2r,                   qw, (long)NE * NE);
        dcopy(w2r + (long)NE * NE,   kw, (long)NE * NE);
        dcopy(w2r + 2L * NE * NE,    vw, (long)NE * NE);
        dcopy(cbias,        qb, NE);
        dcopy(cbias + NE,   kb, NE);
        dcopy(cbias + 2*NE, vb, NE);

        k_rms512<<<CDIV(MA, 4), 256, 0, stream>>>(xenc, hbuf, MA);
        // qkv -> fcbuf [3000][1536]: q cols 0..511, k 512..1023, v 1024..1535
        gemm_mf(stream, hbuf, w2r, cbias, fcbuf, MA, 3 * NE, NE, NE, NE, 3 * NE,
                0,0,0,0,0,0, 1,1, 1.f, 0.f, 0);
        // rms over q+k heads (first 16 of 24 chunks of 64)
        k_rms_heads<64><<<CDIV((long)MA * 16, 4), 256, 0, stream>>>(fcbuf, (long)MA * 16, 16, 3 * NE);
        // QK^T (MFMA, K=64)
        gemm_mf(stream, fcbuf, fcbuf + NE, nullptr, sc, TA, TA, EHD, 3 * NE, 3 * NE, TA,
                (long)TA * 3 * NE, EHD, (long)TA * 3 * NE, EHD, (long)EH * TA * TA, (long)TA * TA,
                NB * EH, EH, 0.125f, 0.f, 0);
        k_softmax<<<CDIV((long)NB * EH * TA, 4), 256, 0, stream>>>(sc, EH, TA, TA, 0, nullptr, (long)NB * EH * TA);
        // PV (fp32)
        gemm(stream, false, sc, fcbuf + 2 * NE, nullptr, obuf, TA, EHD, TA, TA, 3 * NE, NE,
             (long)EH * TA * TA, (long)TA * TA, (long)TA * 3 * NE, EHD, (long)TA * NE, EHD,
             NB * EH, EH, 1.f, 0.f, 0);
        k_decorrelate<64><<<CDIV((long)MA * EH, 4), 256, 0, stream>>>(obuf, fcbuf + 2 * NE, (long)MA * EH, EH, 3 * NE, 0);
        gemm_mf(stream, obuf, ow, ob, xenc, MA, NE, NE, NE, NE, NE, 0,0,0,0,0,0, 1,1, 1.f, 1.f, 0);

        k_rms512<<<CDIV(MA, 4), 256, 0, stream>>>(xenc, hbuf, MA);
        gemm_mf(stream, hbuf, fw, fb, fcbuf, MA, 2048, NE, NE, NE, 2048, 0,0,0,0,0,0, 1,1, 1.f, 0.f, 1);
        gemm_mf(stream, fcbuf, pw, pb, xenc, MA, NE, 2048, 2048, 2048, NE, 0,0,0,0,0,0, 1,1, 1.f, 1.f, 0);
    }

    // ---- cross K/V from encoder output (fused into audkv [3000][1024]) ----
    dcopy(w2r,                 ckw, (long)NE * NE);
    dcopy(w2r + (long)NE * NE, cvw, (long)NE * NE);
    dcopy(cbias,      ckb, NE);
    dcopy(cbias + NE, cvb, NE);
    k_rms512<<<CDIV(MA, 4), 256, 0, stream>>>(xenc, hbuf, MA);
    gemm_mf(stream, hbuf, w2r, cbias, audkv, MA, 2 * NE, NE, NE, NE, 2 * NE,
            0,0,0,0,0,0, 1,1, 1.f, 0.f, 0);
    k_rms_heads<32><<<CDIV((long)MA * DHN, 8), 256, 0, stream>>>(audkv, (long)MA * DHN, DHN, 2 * NE);

    // ---- decoder ----
    k_embed<<<CDIV((long)NB * LQ * NE, 256), 256, 0, stream>>>(ids, embw, pose, ctx);
    k_rms512<<<CDIV(MD, 4), 256, 0, stream>>>(ctx, ctx, MD);
    k_ropetab<<<CDIV(LQ * 16, 256), 256, 0, stream>>>(ctab, stab);

    k_bcast_pos<<<CDIV((long)LQ * NE, 256), 256, 0, stream>>>(pose, q0r, 1);
    k_rms512<<<CDIV(LQ, 4), 256, 0, stream>>>(q0r, q0r, LQ);
    gemm_mf(stream, q0r, sqw, sqb, qh, LQ, NE, NE, NE, NE, NE, 0,0,0,0,0,0, 1,1, 1.f, 0.f, 0);
    k_rope<<<CDIV((long)LQ * DHN * 16, 256), 256, 0, stream>>>(qh, 1, 0, NE, ctab, stab);
    k_rms_heads<32><<<CDIV((long)LQ * DHN, 8), 256, 0, stream>>>(qh, (long)LQ * DHN, DHN, NE);

    // fused self K/V -> selfkv [1792][1024]
    dcopy(w2r,                 skw, (long)NE * NE);
    dcopy(w2r + (long)NE * NE, svw, (long)NE * NE);
    dcopy(cbias,      skb, NE);
    dcopy(cbias + NE, svb, NE);
    gemm_mf(stream, ctx, w2r, cbias, selfkv, MD, 2 * NE, NE, NE, NE, 2 * NE,
            0,0,0,0,0,0, 1,1, 1.f, 0.f, 0);
    k_rope<<<CDIV((long)NB * LQ * DHN * 16, 256), 256, 0, stream>>>(selfkv, NB, 1, 2 * NE, ctab, stab);
    k_rms_heads<32><<<CDIV((long)MD * DHN, 8), 256, 0, stream>>>(selfkv, (long)MD * DHN, DHN, 2 * NE);

    // self-attention (qh shared across batch: sAb = 0)
    gemm_mf(stream, qh, selfkv, nullptr, sc, LQ, LQ, HDD, NE, 2 * NE, LQ,
            0, HDD, (long)LQ * 2 * NE, HDD, (long)DHN * LQ * LQ, (long)LQ * LQ,
            NB * DHN, DHN, dscale, 0.f, 0);
    k_softmax<<<CDIV((long)NB * DHN * LQ, 4), 256, 0, stream>>>(sc, DHN, LQ, LQ, 1, ids, (long)NB * DHN * LQ);
    gemm(stream, false, sc, selfkv + NE, nullptr, odec, LQ, HDD, LQ, LQ, 2 * NE, NE,
         (long)DHN * LQ * LQ, (long)LQ * LQ, (long)LQ * 2 * NE, HDD, (long)LQ * NE, HDD,
         NB * DHN, DHN, 1.f, 0.f, 0);
    k_decorrelate<32><<<CDIV((long)MD * DHN, 8), 256, 0, stream>>>(odec, selfkv + NE, (long)MD * DHN, DHN, 2 * NE, 0);
    k_bcast_pos<<<CDIV((long)NB * LQ * NE, 256), 256, 0, stream>>>(pose, res, NB);
    gemm_mf(stream, odec, soww, sob, res, MD, NE, NE, NE, NE, NE, 0,0,0,0,0,0, 1,1, 1.f, 1.f, 0);

    // cross-attention
    k_rms512<<<CDIV(MD, 4), 256, 0, stream>>>(res, t1, MD);
    gemm_mf(stream, t1, cqw, cqb, qh, MD, NE, NE, NE, NE, NE, 0,0,0,0,0,0, 1,1, 1.f, 0.f, 0);
    k_rope<<<CDIV((long)NB * LQ * DHN * 16, 256), 256, 0, stream>>>(qh, NB, 0, NE, ctab, stab);
    k_rms_heads<32><<<CDIV((long)MD * DHN, 8), 256, 0, stream>>>(qh, (long)MD * DHN, DHN, NE);
    gemm_mf(stream, qh, audkv, nullptr, sc, LQ, TA, HDD, NE, 2 * NE, TA,
            (long)LQ * NE, HDD, (long)TA * 2 * NE, HDD, (long)DHN * LQ * TA, (long)LQ * TA,
            NB * DHN, DHN, dscale, 0.f, 0);
    k_softmax<<<CDIV((long)NB * DHN * LQ, 4), 256, 0, stream>>>(sc, DHN, LQ, TA, 0, nullptr, (long)NB * DHN * LQ);
    gemm(stream, false, sc, audkv + NE, nullptr, odec, LQ, HDD, TA, TA, 2 * NE, NE,
         (long)DHN * LQ * TA, (long)LQ * TA, (long)TA * 2 * NE, HDD, (long)LQ * NE, HDD,
         NB * DHN, DHN, 1.f, 0.f, 0);
    gemm_mf(stream, odec, coww, cob, res, MD, NE, NE, NE, NE, NE, 0,0,0,0,0,0, 1,1, 1.f, 1.f, 0);

    // decoder MLP (fcbuf free again: selfkv/audkv dead)
    k_rms512<<<CDIV(MD, 4), 256, 0, stream>>>(res, t1, MD);
    gemm_mf(stream, t1, fcw, fcb, fcbuf, MD, 2048, NE, NE, NE, 2048, 0,0,0,0,0,0, 1,1, 1.f, 0.f, 1);
    gemm_mf(stream, fcbuf, pjw, pjb, res, MD, NE, 2048, 2048, 2048, NE, 0,0,0,0,0,0, 1,1, 1.f, 1.f, 0);

    // logits
    k_rms512<<<CDIV(MD, 4), 256, 0, stream>>>(res, t1, MD);
    gemm_mf(stream, t1, embw, nullptr, out, MD, OV, NE, NE, NE, OV,
            0,0,0,0,0,0, 1,1, 1.f, 0.f, 0);
}

// Round 3
// 2997.139 us; speedup vs baseline: 1.9242x; 1.0723x over previous
//
#include <hip/hip_runtime.h>
#include <math.h>

#define CDIV(a,b) (((a)+(b)-1)/(b))

static constexpr int NE  = 512;   // n_embed
static constexpr int EH  = 8;     // encoder heads
static constexpr int EHD = 64;    // encoder head dim
static constexpr int DHN = 16;    // decoder heads
static constexpr int HDD = 32;    // decoder head dim
static constexpr int NM  = 80;    // mels
static constexpr int TMl = 1500;  // mel time
static constexpr int TP  = 1502;  // padded time
static constexpr int TA  = 750;   // audio ctx
static constexpr int LQ  = 448;   // text ctx
static constexpr int NB  = 4;     // batch
static constexpr int OV  = 51904; // padded vocab

typedef __attribute__((ext_vector_type(8))) short bf16x8;
typedef __attribute__((ext_vector_type(8))) unsigned short us8;
typedef __attribute__((ext_vector_type(4))) float f32x4;

// split helper: hi = trunc-to-bf16(x), lo = bf16(x - hi). (Ootomo bf16x3)
__device__ __forceinline__ void split1(float f, unsigned short& h, unsigned short& l) {
    unsigned bu = __float_as_uint(f);
    unsigned hb = bu & 0xffff0000u;
    h = (unsigned short)(hb >> 16);
    l = (unsigned short)(__float_as_uint(f - __uint_as_float(hb)) >> 16);
}

// ---------------- elementwise / layout kernels ----------------

__global__ void k_transpose_mels_s(const float* __restrict__ mels,
                                   unsigned short* __restrict__ hi,
                                   unsigned short* __restrict__ lo) {
    long idx = (long)blockIdx.x * blockDim.x + threadIdx.x;
    long total = (long)NB * TP * NM;
    if (idx >= total) return;
    int ci = (int)(idx % NM);
    int t  = (int)((idx / NM) % TP);
    int b  = (int)(idx / ((long)NM * TP));
    float v = 0.f;
    if (t >= 1 && t <= TMl) v = mels[((long)b * NM + ci) * TMl + (t - 1)];
    unsigned short h, l; split1(v, h, l);
    hi[idx] = h; lo[idx] = l;
}

__global__ void k_zero_x1t_pads_s(unsigned short* __restrict__ hi, unsigned short* __restrict__ lo) {
    int idx = blockIdx.x * blockDim.x + threadIdx.x;
    if (idx >= NB * 2 * NE) return;
    int c = idx % NE;
    int r = (idx / NE) % 2;
    int b = idx / (NE * 2);
    int t = r ? (TP - 1) : 0;
    long o = ((long)b * TP + t) * NE + c;
    hi[o] = 0; lo[o] = 0;
}

__global__ void k_repack_w_s(const float* __restrict__ w,
                             unsigned short* __restrict__ hi, unsigned short* __restrict__ lo,
                             int O, int I) {
    // w[o][i][k] -> planes[o][k*I + i]
    long idx = (long)blockIdx.x * blockDim.x + threadIdx.x;
    long total = (long)O * I * 3;
    if (idx >= total) return;
    int k = (int)(idx % 3);
    int i = (int)((idx / 3) % I);
    int o = (int)(idx / ((long)3 * I));
    unsigned short h, l; split1(w[idx], h, l);
    long d = (long)o * (3 * I) + k * I + i;
    hi[d] = h; lo[d] = l;
}

__global__ void k_add_encpos(float* __restrict__ x) {
    long idx = (long)blockIdx.x * blockDim.x + threadIdx.x;
    long total = (long)NB * TA * NE;
    if (idx >= total) return;
    int c = (int)(idx % NE);
    int t = (int)((idx / NE) % TA);
    double inc = log(10000.0) / 255.0;
    int j = c & 255;
    double st = (double)t * exp(-inc * (double)j);
    float p = (c < 256) ? (float)sin(st) : (float)cos(st);
    x[idx] += p;
}

__global__ void k_embed(const int* __restrict__ ids, const float* __restrict__ ew,
                        const float* __restrict__ pos, float* __restrict__ ctx) {
    long idx = (long)blockIdx.x * blockDim.x + threadIdx.x;
    long total = (long)NB * LQ * NE;
    if (idx >= total) return;
    int c = (int)(idx % NE);
    int t = (int)((idx / NE) % LQ);
    int b = (int)(idx / ((long)NE * LQ));
    int id = ids[b * LQ + t];
    float v = ew[(long)id * NE + c] * 22.62741699796952f;
    if (t >= 1) v += pos[(long)(t - 1) * NE + c];
    ctx[idx] = v;
}

__global__ void k_bcast_pos(const float* __restrict__ pos, float* __restrict__ dst, int Bn) {
    long idx = (long)blockIdx.x * blockDim.x + threadIdx.x;
    long total = (long)Bn * LQ * NE;
    if (idx >= total) return;
    int c = (int)(idx % NE);
    int t = (int)((idx / NE) % LQ);
    dst[idx] = pos[(long)t * NE + c];
}

__global__ void k_ropetab(float* __restrict__ ctab, float* __restrict__ stab) {
    int idx = blockIdx.x * blockDim.x + threadIdx.x;
    if (idx >= LQ * 16) return;
    int m = idx % 16;
    int t = idx / 16;
    double inv = pow(10000.0, -(double)(2 * m) / 32.0);
    double f = (double)t * inv;
    ctab[idx] = (float)cos(f);
    stab[idx] = (float)sin(f);
}

__global__ void k_rope(float* __restrict__ x, int Bn, int shiftK, int RS,
                       const float* __restrict__ ctab, const float* __restrict__ stab) {
    long idx = (long)blockIdx.x * blockDim.x + threadIdx.x;
    long total = (long)Bn * LQ * DHN * 16;
    if (idx >= total) return;
    int m = (int)(idx % 16);
    int h = (int)((idx / 16) % DHN);
    int t = (int)((idx / (16 * DHN)) % LQ);
    int b = (int)(idx / ((long)16 * DHN * LQ));
    int tt = shiftK ? (t > 0 ? t - 1 : 0) : t;
    float c = ctab[tt * 16 + m];
    float s = stab[tt * 16 + m];
    long base = ((long)b * LQ + t) * RS + h * HDD;
    float x1 = x[base + m];
    float x2 = x[base + 16 + m];
    x[base + m]      = x1 * c + x2 * s;
    x[base + 16 + m] = -x1 * s + x2 * c;
}

// ---------------- rms / decorrelate / softmax ----------------

// rms over 512-wide rows -> split planes
__global__ void k_rms512s(const float* __restrict__ src,
                          unsigned short* __restrict__ hi, unsigned short* __restrict__ lo,
                          int rows) {
    int wave = blockIdx.x * (blockDim.x >> 6) + (threadIdx.x >> 6);
    int lane = threadIdx.x & 63;
    if (wave >= rows) return;
    const float* s = src + (long)wave * NE;
    float4 a = *(const float4*)(s + lane * 4);
    float4 b = *(const float4*)(s + 256 + lane * 4);
    float ss = a.x*a.x + a.y*a.y + a.z*a.z + a.w*a.w
             + b.x*b.x + b.y*b.y + b.z*b.z + b.w*b.w;
    for (int m = 32; m >= 1; m >>= 1) ss += __shfl_xor(ss, m, 64);
    float sc = rsqrtf(ss / 512.f + 1e-6f);
    float fa[4] = {a.x*sc, a.y*sc, a.z*sc, a.w*sc};
    float fb[4] = {b.x*sc, b.y*sc, b.z*sc, b.w*sc};
    ushort4 ha, la, hb, lb;
    split1(fa[0], ha.x, la.x); split1(fa[1], ha.y, la.y);
    split1(fa[2], ha.z, la.z); split1(fa[3], ha.w, la.w);
    split1(fb[0], hb.x, lb.x); split1(fb[1], hb.y, lb.y);
    split1(fb[2], hb.z, lb.z); split1(fb[3], hb.w, lb.w);
    long base = (long)wave * NE;
    *(ushort4*)(hi + base + lane * 4) = ha;
    *(ushort4*)(lo + base + lane * 4) = la;
    *(ushort4*)(hi + base + 256 + lane * 4) = hb;
    *(ushort4*)(lo + base + 256 + lane * 4) = lb;
}

// generalized in-place head rms: chunk rr -> t = rr/CU, c = rr%CU
template<int D>
__global__ void k_rms_heads(float* __restrict__ x, long nchunks, int CU, int RS) {
    const int RPW = 64 / D;
    long wave = (long)blockIdx.x * (blockDim.x >> 6) + (threadIdx.x >> 6);
    int lane = threadIdx.x & 63;
    long rr = wave * RPW + lane / D;
    if (rr >= nchunks) return;
    int col = lane % D;
    long idx = (rr / CU) * (long)RS + (rr % CU) * D + col;
    float v = x[idx];
    float ss = v * v;
    for (int m = D / 2; m >= 1; m >>= 1) ss += __shfl_xor(ss, m, 64);
    x[idx] = v * rsqrtf(ss / (float)D + 1e-6f);
}

// decorrelate, emitting split planes of o (o packed [nchunks][D]; v strided)
template<int D>
__global__ void k_decorr_s(const float* __restrict__ o, const float* __restrict__ v,
                           unsigned short* __restrict__ hi, unsigned short* __restrict__ lo,
                           long nchunks, int CU, int vRS, int vOff) {
    const int RPW = 64 / D;
    long wave = (long)blockIdx.x * (blockDim.x >> 6) + (threadIdx.x >> 6);
    int lane = threadIdx.x & 63;
    long rr = wave * RPW + lane / D;
    if (rr >= nchunks) return;
    int col = lane % D;
    long oidx = rr * D + col;
    long vidx = (rr / CU) * (long)vRS + vOff + (rr % CU) * D + col;
    float ov = o[oidx];
    float vv = v[vidx];
    float dov = ov * vv;
    float dvv = vv * vv;
    for (int m = D / 2; m >= 1; m >>= 1) {
        dov += __shfl_xor(dov, m, 64);
        dvv += __shfl_xor(dvv, m, 64);
    }
    float nv = sqrtf(dvv);
    float c = fmaxf(nv, 1e-9f);
    float res = ov - (dov / (c * c)) * vv;
    unsigned short h, l; split1(res, h, l);
    hi[oidx] = h; lo[oidx] = l;
}

// plain split (weights / odec / embw)
__global__ void k_split(const float* __restrict__ x, unsigned short* __restrict__ hi,
                        unsigned short* __restrict__ lo, long n4)
{
    long i = (long)blockIdx.x * blockDim.x + threadIdx.x;
    if (i >= n4) return;
    float4 v = ((const float4*)x)[i];
    ushort4 h, l;
    split1(v.x, h.x, l.x); split1(v.y, h.y, l.y);
    split1(v.z, h.z, l.z); split1(v.w, h.w, l.w);
    ((ushort4*)hi)[i] = h;
    ((ushort4*)lo)[i] = l;
}

__global__ void k_softmax(float* __restrict__ s, int H, int Lq, int Lk,
                          int causal, const int* __restrict__ ids, long nrows) {
    long row = (long)blockIdx.x * (blockDim.x >> 6) + (threadIdx.x >> 6);
    if (row >= nrows) return;
    int lane = threadIdx.x & 63;
    int qt = (int)(row % Lq);
    long z = row / Lq;
    int b = (int)(z / H);
    float* p = s + row * (long)Lk;
    int cnt = (Lk + 63) >> 6;
    float vals[12];
    float mx = -INFINITY;
    for (int i = 0; i < cnt; i++) {
        int k = lane + (i << 6);
        float v = -INFINITY;
        if (k < Lk) {
            v = p[k];
            if (causal && k > qt) v = -INFINITY;
            if (ids && ids[(long)b * Lk + k] == 0) v = -INFINITY;
        }
        vals[i] = v;
        mx = fmaxf(mx, v);
    }
    for (int m = 32; m >= 1; m >>= 1) mx = fmaxf(mx, __shfl_xor(mx, m, 64));
    float sum = 0.f;
    for (int i = 0; i < cnt; i++) {
        float e = expf(vals[i] - mx);
        vals[i] = e;
        sum += e;
    }
    for (int m = 32; m >= 1; m >>= 1) sum += __shfl_xor(sum, m, 64);
    float inv = 1.f / sum;
    for (int i = 0; i < cnt; i++) {
        int k = lane + (i << 6);
        if (k < Lk) p[k] = vals[i] * inv;
    }
}

// ---------------- fp32 batched GEMM (PV only) ----------------

template<bool TRANSB>
__global__ __launch_bounds__(256) void k_gemm(
    const float* __restrict__ A, const float* __restrict__ Bm,
    const float* __restrict__ bias, float* __restrict__ C,
    int M, int N, int K, int lda, int ldb, int ldc,
    long sAb, long sAh, long sBb, long sBh, long sCb, long sCh, int H,
    float alpha, float beta, int act)
{
    __shared__ __align__(16) float As[16][68];
    __shared__ __align__(16) float Bs[16][68];
    int z = blockIdx.z;
    int bb = z / H, hh = z % H;
    A  += (long)bb * sAb + (long)hh * sAh;
    Bm += (long)bb * sBb + (long)hh * sBh;
    C  += (long)bb * sCb + (long)hh * sCh;
    int m0 = blockIdx.y * 64, n0 = blockIdx.x * 64;
    int tid = threadIdx.x;
    int tm0 = (tid / 16) * 4, tn0 = (tid % 16) * 4;
    float acc[4][4] = {};
    for (int k0 = 0; k0 < K; k0 += 16) {
        {
            int k = tid & 15, mr = tid >> 4;
            #pragma unroll
            for (int i = 0; i < 4; i++) {
                int m = mr + i * 16;
                float v = 0.f;
                if (m0 + m < M && k0 + k < K) v = A[(long)(m0 + m) * lda + k0 + k];
                As[k][m] = v;
            }
            if (TRANSB) {
                #pragma unroll
                for (int i = 0; i < 4; i++) {
                    int n = mr + i * 16;
                    float v = 0.f;
                    if (n0 + n < N && k0 + k < K) v = Bm[(long)(n0 + n) * ldb + k0 + k];
                    Bs[k][n] = v;
                }
            } else {
                int n = tid & 63, kr = tid >> 6;
                #pragma unroll
                for (int i = 0; i < 4; i++) {
                    int k2 = kr + i * 4;
                    float v = 0.f;
                    if (k0 + k2 < K && n0 + n < N) v = Bm[(long)(k0 + k2) * ldb + n0 + n];
                    Bs[k2][n] = v;
                }
            }
        }
        __syncthreads();
        #pragma unroll
        for (int kk = 0; kk < 16; kk++) {
            float4 av = *(const float4*)&As[kk][tm0];
            float4 bv = *(const float4*)&Bs[kk][tn0];
            float aa[4] = {av.x, av.y, av.z, av.w};
            float bbv[4] = {bv.x, bv.y, bv.z, bv.w};
            #pragma unroll
            for (int i = 0; i < 4; i++)
                #pragma unroll
                for (int j = 0; j < 4; j++)
                    acc[i][j] += aa[i] * bbv[j];
        }
        __syncthreads();
    }
    #pragma unroll
    for (int i = 0; i < 4; i++) {
        int m = m0 + tm0 + i;
        if (m >= M) continue;
        #pragma unroll
        for (int j = 0; j < 4; j++) {
            int n = n0 + tn0 + j;
            if (n >= N) continue;
            float v = alpha * acc[i][j];
            if (bias) v += bias[n];
            long off = (long)m * ldc + n;
            if (beta != 0.f) v += beta * C[off];
            if (act) v = 0.5f * v * (1.f + erff(v * 0.70710678118654752f));
            C[off] = v;
        }
    }
}

static inline void gemm(hipStream_t st, bool tb, const float* A, const float* Bm,
                        const float* bias, float* C, int M, int N, int K,
                        int lda, int ldb, int ldc,
                        long sAb, long sAh, long sBb, long sBh, long sCb, long sCh,
                        int Z, int H, float alpha, float beta, int act)
{
    dim3 g(CDIV(N, 64), CDIV(M, 64), Z), blk(256);
    if (tb) k_gemm<true ><<<g, blk, 0, st>>>(A, Bm, bias, C, M, N, K, lda, ldb, ldc,
                                             sAb, sAh, sBb, sBh, sCb, sCh, H, alpha, beta, act);
    else    k_gemm<false><<<g, blk, 0, st>>>(A, Bm, bias, C, M, N, K, lda, ldb, ldc,
                                             sAb, sAh, sBb, sBh, sCb, sCh, H, alpha, beta, act);
}

// ---------------- MFMA GEMM, fp32 sources with fused split (QK^T only) ----------------

__global__ __launch_bounds__(256, 4) void k_gemm_mf(
    const float* __restrict__ A, const float* __restrict__ B,
    const float* __restrict__ bias, float* __restrict__ C,
    int M, int N, int K, int lda, int ldb, int ldc,
    long sAb, long sAh, long sBb, long sBh, long sCb, long sCh, int H,
    int gx, int gy, float alpha, float beta, int act)
{
    __shared__ __align__(16) unsigned short lds[16384]; // 32 KB: Ah,Al,Bh,Bl
    int nwg = gridDim.x;
    int flat = blockIdx.x;
    int q8 = nwg >> 3, r8 = nwg & 7;
    int xcd = flat & 7, idx = flat >> 3;
    int wg = (xcd < r8 ? xcd * (q8 + 1) : r8 * (q8 + 1) + (xcd - r8) * q8) + idx;
    int my = wg % gy;
    int t2 = wg / gy;
    int nx = t2 % gx;
    int z  = t2 / gx;
    int bb = z / H, hh = z % H;
    A += (long)bb * sAb + (long)hh * sAh;
    B += (long)bb * sBb + (long)hh * sBh;
    C += (long)bb * sCb + (long)hh * sCh;
    int m0 = my * 128, n0 = nx * 128;
    const int tid = threadIdx.x;
    const int wid = tid >> 6, lane = tid & 63;
    const int wm = wid >> 1, wn = wid & 1;
    const int lr = lane & 15, lk = lane >> 4;
    const int rA = tid >> 2, g = tid & 3;

    f32x4 acc[4][4] = {};

    for (int k0 = 0; k0 < K; k0 += 32) {
        __syncthreads();
        int kk = k0 + g * 8;
        bool kv = kk < K;
        #pragma unroll
        for (int half = 0; half < 2; ++half) {
            int r = rA + half * 64;
            int off = r * 32 + (g ^ ((r >> 1) & 3)) * 8;
            {
                float4 f0 = {0,0,0,0}, f1 = {0,0,0,0};
                if (kv && m0 + r < M) {
                    const float* p = A + (long)(m0 + r) * lda + kk;
                    f0 = *(const float4*)p;
                    f1 = *(const float4*)(p + 4);
                }
                float ff[8] = {f0.x,f0.y,f0.z,f0.w,f1.x,f1.y,f1.z,f1.w};
                us8 h, l;
                #pragma unroll
                for (int j = 0; j < 8; ++j) {
                    unsigned short hh2, ll2; split1(ff[j], hh2, ll2);
                    h[j] = hh2; l[j] = ll2;
                }
                *(us8*)(lds + off) = h;
                *(us8*)(lds + 4096 + off) = l;
            }
            {
                float4 f0 = {0,0,0,0}, f1 = {0,0,0,0};
                if (kv && n0 + r < N) {
                    const float* p = B + (long)(n0 + r) * ldb + kk;
                    f0 = *(const float4*)p;
                    f1 = *(const float4*)(p + 4);
                }
                float ff[8] = {f0.x,f0.y,f0.z,f0.w,f1.x,f1.y,f1.z,f1.w};
                us8 h, l;
                #pragma unroll
                for (int j = 0; j < 8; ++j) {
                    unsigned short hh2, ll2; split1(ff[j], hh2, ll2);
                    h[j] = hh2; l[j] = ll2;
                }
                *(us8*)(lds + 8192 + off) = h;
                *(us8*)(lds + 12288 + off) = l;
            }
        }
        __syncthreads();
        bf16x8 ah[4], al[4];
        #pragma unroll
        for (int i = 0; i < 4; ++i) {
            int ra = wm * 64 + i * 16 + lr;
            int ao = ra * 32 + (lk ^ ((ra >> 1) & 3)) * 8;
            ah[i] = *(const bf16x8*)(lds + ao);
            al[i] = *(const bf16x8*)(lds + 4096 + ao);
        }
        #pragma unroll
        for (int j = 0; j < 4; ++j) {
            int rb = wn * 64 + j * 16 + lr;
            int bo = rb * 32 + (lk ^ ((rb >> 1) & 3)) * 8;
            bf16x8 bh = *(const bf16x8*)(lds + 8192 + bo);
            bf16x8 bl = *(const bf16x8*)(lds + 12288 + bo);
            #pragma unroll
            for (int i = 0; i < 4; ++i) {
                acc[i][j] = __builtin_amdgcn_mfma_f32_16x16x32_bf16(ah[i], bh, acc[i][j], 0, 0, 0);
                acc[i][j] = __builtin_amdgcn_mfma_f32_16x16x32_bf16(ah[i], bl, acc[i][j], 0, 0, 0);
                acc[i][j] = __builtin_amdgcn_mfma_f32_16x16x32_bf16(al[i], bh, acc[i][j], 0, 0, 0);
            }
        }
    }
    #pragma unroll
    for (int i = 0; i < 4; ++i) {
        int rowb = m0 + wm * 64 + i * 16 + lk * 4;
        #pragma unroll
        for (int j = 0; j < 4; ++j) {
            int col = n0 + wn * 64 + j * 16 + lr;
            if (col >= N) continue;
            float bi = bias ? bias[col] : 0.f;
            #pragma unroll
            for (int qi = 0; qi < 4; ++qi) {
                int row = rowb + qi;
                if (row >= M) continue;
                float v = alpha * acc[i][j][qi] + bi;
                long off = (long)row * ldc + col;
                if (beta != 0.f) v += beta * C[off];
                if (act) v = 0.5f * v * (1.f + erff(v * 0.70710678118654752f));
                C[off] = v;
            }
        }
    }
}

static inline void gemm_mf(hipStream_t st, const float* A, const float* B, const float* bias,
                           float* C, int M, int N, int K, int lda, int ldb, int ldc,
                           long sAb, long sAh, long sBb, long sBh, long sCb, long sCh,
                           int Z, int H, float alpha, float beta, int act)
{
    int gx = CDIV(N, 128), gy = CDIV(M, 128);
    dim3 g((unsigned)(gx * gy * Z));
    k_gemm_mf<<<g, 256, 0, st>>>(A, B, bias, C, M, N, K, lda, ldb, ldc,
                                 sAb, sAh, sBb, sBh, sCb, sCh, H, gx, gy, alpha, beta, act);
}

// ---------------- MFMA GEMM, pre-split bf16 hi/lo operands (main path) ----------------
// C = act(A . B^T + bias [+ beta*C]); planes are bf16 with fp32-matrix leading dims.
// Staging is pure 16B load -> swizzled ds_write_b128: zero conversion VALU.
// Optional split-output epilogue (osplit) writes hi/lo planes (for FC-GELU outputs).

__global__ __launch_bounds__(256, 4) void k_gemm_bs(
    const unsigned short* __restrict__ Ah, const unsigned short* __restrict__ Al,
    const unsigned short* __restrict__ Bh, const unsigned short* __restrict__ Bl,
    const float* __restrict__ bias, float* __restrict__ C,
    unsigned short* __restrict__ Chi, unsigned short* __restrict__ Clo,
    int M, int N, int K, int lda, int ldb, int ldc,
    long sAb, long sCb, int gx, int gy, float beta, int act, int osplit)
{
    __shared__ __align__(16) unsigned short lds[16384]; // 32 KB
    int nwg = gridDim.x;
    int flat = blockIdx.x;
    int q8 = nwg >> 3, r8 = nwg & 7;
    int xcd = flat & 7, idx = flat >> 3;
    int wg = (xcd < r8 ? xcd * (q8 + 1) : r8 * (q8 + 1) + (xcd - r8) * q8) + idx;
    int my = wg % gy;
    int t2 = wg / gy;
    int nx = t2 % gx;
    int bb = t2 / gx;
    Ah += (long)bb * sAb; Al += (long)bb * sAb;
    int m0 = my * 128, n0 = nx * 128;
    const int tid = threadIdx.x;
    const int wid = tid >> 6, lane = tid & 63;
    const int wm = wid >> 1, wn = wid & 1;
    const int lr = lane & 15, lk = lane >> 4;
    const int rA = tid >> 2, g = tid & 3;

    f32x4 acc[4][4] = {};

    for (int k0 = 0; k0 < K; k0 += 32) {
        __syncthreads();
        int kk = k0 + g * 8;
        bool kv = kk < K;
        #pragma unroll
        for (int half = 0; half < 2; ++half) {
            int r = rA + half * 64;
            int off = r * 32 + (g ^ ((r >> 1) & 3)) * 8;
            us8 vh = {0,0,0,0,0,0,0,0}, vl = {0,0,0,0,0,0,0,0};
            if (kv && m0 + r < M) {
                long ao = (long)(m0 + r) * lda + kk;
                vh = *(const us8*)(Ah + ao);
                vl = *(const us8*)(Al + ao);
            }
            *(us8*)(lds + off) = vh;
            *(us8*)(lds + 4096 + off) = vl;
            us8 wh = {0,0,0,0,0,0,0,0}, wl = {0,0,0,0,0,0,0,0};
            if (kv && n0 + r < N) {
                long bo = (long)(n0 + r) * ldb + kk;
                wh = *(const us8*)(Bh + bo);
                wl = *(const us8*)(Bl + bo);
            }
            *(us8*)(lds + 8192 + off) = wh;
            *(us8*)(lds + 12288 + off) = wl;
        }
        __syncthreads();
        bf16x8 ah[4], al[4];
        #pragma unroll
        for (int i = 0; i < 4; ++i) {
            int ra = wm * 64 + i * 16 + lr;
            int ao = ra * 32 + (lk ^ ((ra >> 1) & 3)) * 8;
            ah[i] = *(const bf16x8*)(lds + ao);
            al[i] = *(const bf16x8*)(lds + 4096 + ao);
        }
        #pragma unroll
        for (int j = 0; j < 4; ++j) {
            int rb = wn * 64 + j * 16 + lr;
            int bo = rb * 32 + (lk ^ ((rb >> 1) & 3)) * 8;
            bf16x8 bh = *(const bf16x8*)(lds + 8192 + bo);
            bf16x8 bl = *(const bf16x8*)(lds + 12288 + bo);
            #pragma unroll
            for (int i = 0; i < 4; ++i) {
                acc[i][j] = __builtin_amdgcn_mfma_f32_16x16x32_bf16(ah[i], bh, acc[i][j], 0, 0, 0);
                acc[i][j] = __builtin_amdgcn_mfma_f32_16x16x32_bf16(ah[i], bl, acc[i][j], 0, 0, 0);
                acc[i][j] = __builtin_amdgcn_mfma_f32_16x16x32_bf16(al[i], bh, acc[i][j], 0, 0, 0);
            }
        }
    }
    #pragma unroll
    for (int i = 0; i < 4; ++i) {
        int rowb = m0 + wm * 64 + i * 16 + lk * 4;
        #pragma unroll
        for (int j = 0; j < 4; ++j) {
            int col = n0 + wn * 64 + j * 16 + lr;
            if (col >= N) continue;
            float bi = bias ? bias[col] : 0.f;
            #pragma unroll
            for (int qi = 0; qi < 4; ++qi) {
                int row = rowb + qi;
                if (row >= M) continue;
                float v = acc[i][j][qi] + bi;
                long off2 = (long)bb * sCb + (long)row * ldc + col;
                if (osplit) {
                    if (act) v = 0.5f * v * (1.f + erff(v * 0.70710678118654752f));
                    unsigned short h, l; split1(v, h, l);
                    Chi[off2] = h; Clo[off2] = l;
                } else {
                    if (beta != 0.f) v += beta * C[off2];
                    if (act) v = 0.5f * v * (1.f + erff(v * 0.70710678118654752f));
                    C[off2] = v;
                }
            }
        }
    }
}

static inline void gemm_bs(hipStream_t st,
                           const unsigned short* Ah, const unsigned short* Al,
                           const unsigned short* Bh, const unsigned short* Bl,
                           const float* bias, float* C,
                           unsigned short* Chi, unsigned short* Clo,
                           int M, int N, int K, int lda, int ldb, int ldc,
                           long sAb, long sCb, int Z, float beta, int act, int osplit)
{
    int gx = CDIV(N, 128), gy = CDIV(M, 128);
    dim3 g((unsigned)(gx * gy * Z));
    k_gemm_bs<<<g, 256, 0, st>>>(Ah, Al, Bh, Bl, bias, C, Chi, Clo,
                                 M, N, K, lda, ldb, ldc, sAb, sCb, gx, gy, beta, act, osplit);
}

// ---------------- launcher ----------------

extern "C" void kernel_launch(void* const* d_in, const int* in_sizes, int n_in,
                              void* d_out, int out_size, void* d_ws, size_t ws_size,
                              hipStream_t stream)
{
    const float* mels = (const float*)d_in[0];
    const int*   ids  = (const int*)  d_in[1];
    const float* c1w  = (const float*)d_in[2];
    const float* c1b  = (const float*)d_in[3];
    const float* c2w  = (const float*)d_in[4];
    const float* c2b  = (const float*)d_in[5];
    const float* eqw  = (const float*)d_in[6];
    const float* eqb  = (const float*)d_in[7];
    const float* ekw  = (const float*)d_in[8];
    const float* ekb  = (const float*)d_in[9];
    const float* evw  = (const float*)d_in[10];
    const float* evb  = (const float*)d_in[11];
    const float* eow  = (const float*)d_in[12];
    const float* eob  = (const float*)d_in[13];
    const float* efcw = (const float*)d_in[14];
    const float* efcb = (const float*)d_in[15];
    const float* epjw = (const float*)d_in[16];
    const float* epjb = (const float*)d_in[17];
    const float* sqw  = (const float*)d_in[18];
    const float* sqb  = (const float*)d_in[19];
    const float* skw  = (const float*)d_in[20];
    const float* skb  = (const float*)d_in[21];
    const float* svw  = (const float*)d_in[22];
    const float* svb  = (const float*)d_in[23];
    const float* soww = (const float*)d_in[24];
    const float* sob  = (const float*)d_in[25];
    const float* cqw  = (const float*)d_in[26];
    const float* cqb  = (const float*)d_in[27];
    const float* ckw  = (const float*)d_in[28];
    const float* ckb  = (const float*)d_in[29];
    const float* cvw  = (const float*)d_in[30];
    const float* cvb  = (const float*)d_in[31];
    const float* coww = (const float*)d_in[32];
    const float* cob  = (const float*)d_in[33];
    const float* fcw  = (const float*)d_in[34];
    const float* fcb  = (const float*)d_in[35];
    const float* pjw  = (const float*)d_in[36];
    const float* pjb  = (const float*)d_in[37];
    const float* embw = (const float*)d_in[38];
    const float* pose = (const float*)d_in[39];
    float* out = (float*)d_out;

    float* ws = (float*)d_ws;
    long off = 0;
    auto alloc = [&](long n) { float* p = ws + off; off += n; return p; };
    float* melsT = alloc((long)NB * TP * NM);      // melsT split planes
    float* x1t   = alloc((long)NB * TP * NE);      // x1t split planes
    float* w1r   = alloc(3L * NE * NM);            // conv1 w split planes
    float* w2r   = alloc(3L * NE * NE);            // conv2 w split planes
    float* xenc  = alloc((long)NB * TA * NE);
    float* hbuf  = alloc((long)NB * TA * NE);      // hsp: enc rms split
    float* qbuf  = alloc((long)NB * TA * NE);      // osp: enc decorr split
    float* kbuf  = alloc((long)NB * TA * NE);      // bsp: weight split arena
    float* vbuf  = alloc((long)NB * TA * NE);      // spare
    float* obuf  = alloc((long)NB * TA * NE);      // PV out (fp32)
    float* fcbuf = alloc((long)NB * TA * 2048);    // qkv/selfkv/audkv fp32 | FC split planes
    float* sc    = alloc((long)NB * DHN * LQ * TA);
    float* audk  = alloc((long)NB * TA * NE);      // spare
    float* audv  = alloc((long)NB * TA * NE);      // spare
    float* ctx   = alloc((long)NB * LQ * NE);
    float* q0r   = alloc((long)LQ * NE);
    float* qh    = alloc((long)NB * LQ * NE);
    float* kh    = alloc((long)NB * LQ * NE);      // dsp: dec split arena 2
    float* vh    = alloc((long)NB * LQ * NE);      // csp: dec split arena 1
    float* res   = alloc((long)NB * LQ * NE);
    float* t1    = alloc((long)NB * LQ * NE);      // spare
    float* odec  = alloc((long)NB * LQ * NE);
    float* ctab  = alloc((long)LQ * 16);
    float* stab  = alloc((long)LQ * 16);
    float* cbias = alloc(2048);
    (void)ws_size; (void)in_sizes; (void)n_in; (void)out_size;
    (void)vbuf; (void)audk; (void)audv; (void)t1;

    const int MA = NB * TA;  // 3000 encoder rows
    const int MD = NB * LQ;  // 1792 decoder rows
    const float dscale = 0.17677669529663687f; // 1/sqrt(32)

    typedef unsigned short us;
    // split arenas (hi plane, lo plane)
    us* melH = (us*)melsT;              us* melL = melH + (long)NB * TP * NM;
    us* x1H  = (us*)x1t;                us* x1L  = x1H + (long)NB * TP * NE;
    us* w1H  = (us*)w1r;                us* w1L  = w1H + 3L * NE * NM;
    us* w2H  = (us*)w2r;                us* w2L  = w2H + 3L * NE * NE;
    us* hspH = (us*)hbuf;               us* hspL = hspH + (long)MA * NE;
    us* ospH = (us*)qbuf;               us* ospL = ospH + (long)MA * NE;
    us* bspH = (us*)kbuf;               us* bspL = bspH + 1048576L;     // cap 1M elems
    us* cspH = (us*)vh;                 us* cspL = cspH + (long)MD * NE;
    us* dspH = (us*)kh;                 us* dspL = dspH + (long)MD * NE;
    const long EMW = (long)OV * NE;     // 26,574,848 elems
    us* embH = (us*)ws;                 us* embL = embH + EMW;  // over dead conv/enc region at logits time
    // fused KV fp32 regions inside fcbuf
    float* selfkv = fcbuf;               // [1792][1024]
    float* audkv  = fcbuf + 3000000L;    // [3000][1024]
    // FC-out split planes (reuse fcbuf; previous fp32 contents dead)
    us* fcsH = (us*)fcbuf;

    auto split = [&](const float* x, long n, us* hi, us* lo) {
        k_split<<<dim3((unsigned)CDIV(n / 4, 256)), 256, 0, stream>>>(x, hi, lo, n / 4);
    };
    auto dcopy = [&](float* dst, const float* src, long n) {
        hipMemcpyAsync(dst, src, n * sizeof(float), hipMemcpyDeviceToDevice, stream);
    };
    const long nW = (long)NE * NE;       // 262,144
    const long nFC = 2048L * NE;         // 1,048,576

    // ---- conv front-end (pre-split planes, taps stacked along K) ----
    k_transpose_mels_s<<<CDIV((long)NB * TP * NM, 256), 256, 0, stream>>>(mels, melH, melL);
    k_repack_w_s<<<CDIV(3L * NE * NM, 256), 256, 0, stream>>>(c1w, w1H, w1L, NE, NM);
    k_repack_w_s<<<CDIV(3L * NE * NE, 256), 256, 0, stream>>>(c2w, w2H, w2L, NE, NE);
    k_zero_x1t_pads_s<<<CDIV(NB * 2 * NE, 256), 256, 0, stream>>>(x1H, x1L);
    // conv1 -> x1t split planes (gelu, split epilogue), rows offset +NE
    gemm_bs(stream, melH, melL, w1H, w1L, c1b, nullptr, x1H + NE, x1L + NE,
            TMl, NE, 3 * NM, NM, 3 * NM, NE,
            (long)TP * NM, (long)TP * NE, NB, 0.f, 1, 1);
    // conv2 (stride 2 via lda=2*NE) -> xenc fp32
    gemm_bs(stream, x1H, x1L, w2H, w2L, c2b, xenc, nullptr, nullptr,
            TA, NE, 3 * NE, 2 * NE, 3 * NE, NE,
            (long)TP * NE, (long)TA * NE, NB, 0.f, 1, 0);
    k_add_encpos<<<CDIV((long)NB * TA * NE, 256), 256, 0, stream>>>(xenc);

    // ---- encoder layers ----
    for (int l = 0; l < 2; l++) {
        const float* qw = eqw + (long)l * NE * NE; const float* qb = eqb + l * NE;
        const float* kw = ekw + (long)l * NE * NE; const float* kb = ekb + l * NE;
        const float* vw = evw + (long)l * NE * NE; const float* vb = evb + l * NE;
        const float* ow = eow + (long)l * NE * NE; const float* ob = eob + l * NE;
        const float* fw = efcw + (long)l * 2048 * NE; const float* fb = efcb + l * 2048;
        const float* pw = epjw + (long)l * NE * 2048; const float* pb = epjb + l * NE;

        // split QKV weights into concat planes [1536][512]
        split(qw, nW, bspH,          bspL);
        split(kw, nW, bspH + nW,     bspL + nW);
        split(vw, nW, bspH + 2 * nW, bspL + 2 * nW);
        dcopy(cbias,        qb, NE);
        dcopy(cbias + NE,   kb, NE);
        dcopy(cbias + 2*NE, vb, NE);

        k_rms512s<<<CDIV(MA, 4), 256, 0, stream>>>(xenc, hspH, hspL, MA);
        // qkv -> fcbuf fp32 [3000][1536]
        gemm_bs(stream, hspH, hspL, bspH, bspL, cbias, fcbuf, nullptr, nullptr,
                MA, 3 * NE, NE, NE, NE, 3 * NE, 0, 0, 1, 0.f, 0, 0);
        k_rms_heads<64><<<CDIV((long)MA * 16, 4), 256, 0, stream>>>(fcbuf, (long)MA * 16, 16, 3 * NE);
        // QK^T (fused-convert MFMA, K=64)
        gemm_mf(stream, fcbuf, fcbuf + NE, nullptr, sc, TA, TA, EHD, 3 * NE, 3 * NE, TA,
                (long)TA * 3 * NE, EHD, (long)TA * 3 * NE, EHD, (long)EH * TA * TA, (long)TA * TA,
                NB * EH, EH, 0.125f, 0.f, 0);
        k_softmax<<<CDIV((long)NB * EH * TA, 4), 256, 0, stream>>>(sc, EH, TA, TA, 0, nullptr, (long)NB * EH * TA);
        // PV (fp32)
        gemm(stream, false, sc, fcbuf + 2 * NE, nullptr, obuf, TA, EHD, TA, TA, 3 * NE, NE,
             (long)EH * TA * TA, (long)TA * TA, (long)TA * 3 * NE, EHD, (long)TA * NE, EHD,
             NB * EH, EH, 1.f, 0.f, 0);
        k_decorr_s<64><<<CDIV((long)MA * EH, 4), 256, 0, stream>>>(obuf, fcbuf + 2 * NE, ospH, ospL,
                                                                   (long)MA * EH, EH, 3 * NE, 0);
        split(ow, nW, bspH, bspL);
        gemm_bs(stream, ospH, ospL, bspH, bspL, ob, xenc, nullptr, nullptr,
                MA, NE, NE, NE, NE, NE, 0, 0, 1, 1.f, 0, 0);

        k_rms512s<<<CDIV(MA, 4), 256, 0, stream>>>(xenc, hspH, hspL, MA);
        split(fw, nFC, bspH, bspL);
        // FC -> split planes in fcbuf (gelu fused)
        gemm_bs(stream, hspH, hspL, bspH, bspL, fb, nullptr, fcsH, fcsH + (long)MA * 2048,
                MA, 2048, NE, NE, NE, 2048, 0, 0, 1, 0.f, 1, 1);
        split(pw, nFC, bspH, bspL);
        gemm_bs(stream, fcsH, fcsH + (long)MA * 2048, bspH, bspL, pb, xenc, nullptr, nullptr,
                MA, NE, 2048, 2048, 2048, NE, 0, 0, 1, 1.f, 0, 0);
    }

    // ---- cross K/V from encoder output (fused into audkv fp32 [3000][1024]) ----
    split(ckw, nW, bspH,      bspL);
    split(cvw, nW, bspH + nW, bspL + nW);
    dcopy(cbias,      ckb, NE);
    dcopy(cbias + NE, cvb, NE);
    k_rms512s<<<CDIV(MA, 4), 256, 0, stream>>>(xenc, hspH, hspL, MA);
    gemm_bs(stream, hspH, hspL, bspH, bspL, cbias, audkv, nullptr, nullptr,
            MA, 2 * NE, NE, NE, NE, 2 * NE, 0, 0, 1, 0.f, 0, 0);
    k_rms_heads<32><<<CDIV((long)MA * DHN, 8), 256, 0, stream>>>(audkv, (long)MA * DHN, DHN, 2 * NE);

    // ---- decoder ----
    k_embed<<<CDIV((long)NB * LQ * NE, 256), 256, 0, stream>>>(ids, embw, pose, ctx);
    k_rms512s<<<CDIV(MD, 4), 256, 0, stream>>>(ctx, cspH, cspL, MD);
    k_ropetab<<<CDIV(LQ * 16, 256), 256, 0, stream>>>(ctab, stab);

    k_bcast_pos<<<CDIV((long)LQ * NE, 256), 256, 0, stream>>>(pose, q0r, 1);
    k_rms512s<<<CDIV(LQ, 4), 256, 0, stream>>>(q0r, dspH, dspL, LQ);
    split(sqw, nW, bspH, bspL);
    gemm_bs(stream, dspH, dspL, bspH, bspL, sqb, qh, nullptr, nullptr,
            LQ, NE, NE, NE, NE, NE, 0, 0, 1, 0.f, 0, 0);
    k_rope<<<CDIV((long)LQ * DHN * 16, 256), 256, 0, stream>>>(qh, 1, 0, NE, ctab, stab);
    k_rms_heads<32><<<CDIV((long)LQ * DHN, 8), 256, 0, stream>>>(qh, (long)LQ * DHN, DHN, NE);

    // fused self K/V -> selfkv fp32 [1792][1024]
    split(skw, nW, bspH,      bspL);
    split(svw, nW, bspH + nW, bspL + nW);
    dcopy(cbias,      skb, NE);
    dcopy(cbias + NE, svb, NE);
    gemm_bs(stream, cspH, cspL, bspH, bspL, cbias, selfkv, nullptr, nullptr,
            MD, 2 * NE, NE, NE, NE, 2 * NE, 0, 0, 1, 0.f, 0, 0);
    k_rope<<<CDIV((long)NB * LQ * DHN * 16, 256), 256, 0, stream>>>(selfkv, NB, 1, 2 * NE, ctab, stab);
    k_rms_heads<32><<<CDIV((long)MD * DHN, 8), 256, 0, stream>>>(selfkv, (long)MD * DHN, DHN, 2 * NE);

    // self-attention (fused-convert QK^T; qh shared across batch: sAb = 0)
    gemm_mf(stream, qh, selfkv, nullptr, sc, LQ, LQ, HDD, NE, 2 * NE, LQ,
            0, HDD, (long)LQ * 2 * NE, HDD, (long)DHN * LQ * LQ, (long)LQ * LQ,
            NB * DHN, DHN, dscale, 0.f, 0);
    k_softmax<<<CDIV((long)NB * DHN * LQ, 4), 256, 0, stream>>>(sc, DHN, LQ, LQ, 1, ids, (long)NB * DHN * LQ);
    gemm(stream, false, sc, selfkv + NE, nullptr, odec, LQ, HDD, LQ, LQ, 2 * NE, NE,
         (long)DHN * LQ * LQ, (long)LQ * LQ, (long)LQ * 2 * NE, HDD, (long)LQ * NE, HDD,
         NB * DHN, DHN, 1.f, 0.f, 0);
    k_decorr_s<32><<<CDIV((long)MD * DHN, 8), 256, 0, stream>>>(odec, selfkv + NE, dspH, dspL,
                                                                (long)MD * DHN, DHN, 2 * NE, 0);
    k_bcast_pos<<<CDIV((long)NB * LQ * NE, 256), 256, 0, stream>>>(pose, res, NB);
    split(soww, nW, bspH, bspL);
    gemm_bs(stream, dspH, dspL, bspH, bspL, sob, res, nullptr, nullptr,
            MD, NE, NE, NE, NE, NE, 0, 0, 1, 1.f, 0, 0);

    // cross-attention
    k_rms512s<<<CDIV(MD, 4), 256, 0, stream>>>(res, cspH, cspL, MD);
    split(cqw, nW, bspH, bspL);
    gemm_bs(stream, cspH, cspL, bspH, bspL, cqb, qh, nullptr, nullptr,
            MD, NE, NE, NE, NE, NE, 0, 0, 1, 0.f, 0, 0);
    k_rope<<<CDIV((long)NB * LQ * DHN * 16, 256), 256, 0, stream>>>(qh, NB, 0, NE, ctab, stab);
    k_rms_heads<32><<<CDIV((long)MD * DHN, 8), 256, 0, stream>>>(qh, (long)MD * DHN, DHN, NE);
    gemm_mf(stream, qh, audkv, nullptr, sc, LQ, TA, HDD, NE, 2 * NE, TA,
            (long)LQ * NE, HDD, (long)TA * 2 * NE, HDD, (long)DHN * LQ * TA, (long)LQ * TA,
            NB * DHN, DHN, dscale, 0.f, 0);
    k_softmax<<<CDIV((long)NB * DHN * LQ, 4), 256, 0, stream>>>(sc, DHN, LQ, TA, 0, nullptr, (long)NB * DHN * LQ);
    gemm(stream, false, sc, audkv + NE, nullptr, odec, LQ, HDD, TA, TA, 2 * NE, NE,
         (long)DHN * LQ * TA, (long)LQ * TA, (long)TA * 2 * NE, HDD, (long)LQ * NE, HDD,
         NB * DHN, DHN, 1.f, 0.f, 0);
    split(odec, (long)MD * NE, dspH, dspL);
    split(coww, nW, bspH, bspL);
    gemm_bs(stream, dspH, dspL, bspH, bspL, cob, res, nullptr, nullptr,
            MD, NE, NE, NE, NE, NE, 0, 0, 1, 1.f, 0, 0);

    // decoder MLP (fcbuf free: selfkv/audkv dead)
    k_rms512s<<<CDIV(MD, 4), 256, 0, stream>>>(res, cspH, cspL, MD);
    split(fcw, nFC, bspH, bspL);
    gemm_bs(stream, cspH, cspL, bspH, bspL, fcb, nullptr, fcsH, fcsH + (long)MD * 2048,
            MD, 2048, NE, NE, NE, 2048, 0, 0, 1, 0.f, 1, 1);
    split(pjw, nFC, bspH, bspL);
    gemm_bs(stream, fcsH, fcsH + (long)MD * 2048, bspH, bspL, pjb, res, nullptr, nullptr,
            MD, NE, 2048, 2048, 2048, NE, 0, 0, 1, 1.f, 0, 0);

    // logits: embw split overlays dead ws[0 .. 26.57M floats); A-split lives in vh slot (outside)
    k_rms512s<<<CDIV(MD, 4), 256, 0, stream>>>(res, cspH, cspL, MD);
    split(embw, EMW, embH, embL);
    gemm_bs(stream, cspH, cspL, embH, embL, nullptr, out, nullptr, nullptr,
            MD, OV, NE, NE, NE, OV, 0, 0, 1, 0.f, 0, 0);
}